// Round 17
// baseline (194.312 us; speedup 1.0000x reference)
//
#include <hip/hip_runtime.h>
#include <math.h>

typedef __bf16 bf16;
typedef __bf16 bf16x8 __attribute__((ext_vector_type(8)));
typedef __bf16 bf16x4 __attribute__((ext_vector_type(4)));
typedef float  f32x4  __attribute__((ext_vector_type(4)));

#define NSEQ 4096
#define DMODEL 512
#define DHEAD 64
#define MFEAT 512
#define BHEADS 32
#define ROWS_TOTAL 16384

#define NORMALIZER 0.35355339059327373f
#define DIAG_C 0.0625f
#define KEPS 1e-4f

__device__ __forceinline__ float warpReduceSum(float v) {
#pragma unroll
    for (int off = 32; off > 0; off >>= 1) v += __shfl_xor(v, off);
    return v;
}

__device__ __forceinline__ void atomicMaxF(float* addr, float val) {
    int* ai = (int*)addr;
    int cur = __float_as_int(*addr);
    while (__int_as_float(cur) < val) {
        int prev = atomicCAS(ai, cur, __float_as_int(val));
        if (prev == cur) break;
        cur = prev;
    }
}

__device__ __forceinline__ void gload16(const void* g, void* l) {
    __builtin_amdgcn_global_load_lds((const __attribute__((address_space(1))) void*)g,
                                     (__attribute__((address_space(3))) void*)l, 16, 0, 0);
}

// ---------------------------------------------------------------------------
// prep: f32 -> bf16 conversions + weight concat + bias concat.
// pqb written PRE-SWIZZLED per 128B row: byte ^= (feat&7)<<4.
// ---------------------------------------------------------------------------
__global__ __launch_bounds__(256)
void prep_convert(const float* __restrict__ x, const float* __restrict__ Wq,
                  const float* __restrict__ Wk, const float* __restrict__ Wv,
                  const float* __restrict__ Wd, const float* __restrict__ pq,
                  const float* __restrict__ bq, const float* __restrict__ bk,
                  const float* __restrict__ bv,
                  bf16* __restrict__ xb, bf16* __restrict__ Wb,
                  bf16* __restrict__ Wdb, bf16* __restrict__ pqb,
                  float* __restrict__ bcat)
{
    size_t i4 = (size_t)blockIdx.x * 256 + threadIdx.x;
    size_t e0 = i4 * 4;
    if (e0 >= 9471488) return;
    const float* src;
    if (e0 < 8388608) {
        src = x + e0;
        float4 v = *(const float4*)src;
        bf16* d = xb + e0;
        d[0] = (bf16)v.x; d[1] = (bf16)v.y; d[2] = (bf16)v.z; d[3] = (bf16)v.w;
    } else if (e0 < 9175040) {
        size_t c = e0 - 8388608; int wsel = (int)(c >> 18); size_t o = c & 262143;
        src = (wsel == 0 ? Wq : wsel == 1 ? Wk : Wv) + o;
        float4 v = *(const float4*)src;
        bf16* d = Wb + c;
        d[0] = (bf16)v.x; d[1] = (bf16)v.y; d[2] = (bf16)v.z; d[3] = (bf16)v.w;
    } else if (e0 < 9437184) {
        size_t c = e0 - 9175040;
        src = Wd + c;
        float4 v = *(const float4*)src;
        bf16* d = Wdb + c;
        d[0] = (bf16)v.x; d[1] = (bf16)v.y; d[2] = (bf16)v.z; d[3] = (bf16)v.w;
    } else if (e0 < 9469952) {
        size_t c = e0 - 9437184;           // multiple of 4
        src = pq + c;
        float4 v = *(const float4*)src;
        const int feat = (int)(c >> 6), col = (int)(c & 63);
        bf16x4 d4;
        d4[0] = (bf16)v.x; d4[1] = (bf16)v.y; d4[2] = (bf16)v.z; d4[3] = (bf16)v.w;
        const int inrow = (col << 1) ^ ((feat & 7) << 4);
        *(bf16x4*)((char*)pqb + (size_t)feat * 128 + inrow) = d4;
    } else {
        size_t c = e0 - 9469952; int wsel = (int)(c >> 9); size_t o = c & 511;
        src = (wsel == 0 ? bq : wsel == 1 ? bk : bv) + o;
        *(float4*)(bcat + c) = *(const float4*)src;
    }
}

// ---------------------------------------------------------------------------
// bf16 MFMA GEMM, C = A * B^T (+bias)(+resid), 128x128 tile, BK=64.
// MODE 0: A=xb16, B=Wcat[1536x512]; Q->bf16 [bh][n][64]; K->bf16 swizzled rows;
//         V->bf16 transposed [bh][e][n] swizzled.
//         Q/K stripes: LDS-transpose epilogue (vectorized stores).
// MODE 1: A=ctxb16, B=Wd; outF f32 = +bias +resid
// ---------------------------------------------------------------------------
template<int MODE>
__global__ __launch_bounds__(256)
void gemm_mfma(const bf16* __restrict__ A, const bf16* __restrict__ Bw,
               const float* __restrict__ bias, const float* __restrict__ resid,
               bf16* __restrict__ outQ, bf16* __restrict__ outK,
               bf16* __restrict__ outV, float* __restrict__ outF)
{
    __shared__ char smem[32768];
    char* As = smem;
    char* Bs = smem + 16384;
    const int tid = threadIdx.x;
    const int w = tid >> 6, l = tid & 63;
    const int wr = w >> 1, wc = w & 1;
    const int row0 = blockIdx.y << 7;
    const int col0 = blockIdx.x << 7;

    f32x4 acc[4][4] = {};
    const char* Ab = (const char*)A + (size_t)row0 * 1024;
    const char* Bb = (const char*)Bw + (size_t)col0 * 1024;

    for (int kt = 0; kt < 8; ++kt) {
        const int k0b = kt << 7;
#pragma unroll
        for (int i = 0; i < 4; ++i) {
            int off = (i << 12) + (tid << 4);
            int g = off ^ ((off >> 3) & 0x70);
            int grow = g >> 7, gcol = g & 127;
            gload16(Ab + (size_t)grow * 1024 + k0b + gcol, As + (i << 12) + (w << 10));
            gload16(Bb + (size_t)grow * 1024 + k0b + gcol, Bs + (i << 12) + (w << 10));
        }
        __syncthreads();
#pragma unroll
        for (int ks = 0; ks < 2; ++ks) {
            bf16x8 af[4], bb[4];
#pragma unroll
            for (int mi = 0; mi < 4; ++mi) {
                int row = (wr << 6) + (mi << 4) + (l & 15);
                int addr = ((row << 7) + (ks << 6) + ((l >> 4) << 4)) ^ ((row & 7) << 4);
                af[mi] = *(const bf16x8*)(As + addr);
            }
#pragma unroll
            for (int nj = 0; nj < 4; ++nj) {
                int row = (wc << 6) + (nj << 4) + (l & 15);
                int addr = ((row << 7) + (ks << 6) + ((l >> 4) << 4)) ^ ((row & 7) << 4);
                bb[nj] = *(const bf16x8*)(Bs + addr);
            }
#pragma unroll
            for (int mi = 0; mi < 4; ++mi)
#pragma unroll
                for (int nj = 0; nj < 4; ++nj)
                    acc[mi][nj] = __builtin_amdgcn_mfma_f32_16x16x32_bf16(af[mi], bb[nj], acc[mi][nj], 0, 0, 0);
        }
        __syncthreads();
    }

    const int subrow = (l >> 4) << 2;
    const int subcol = l & 15;

    if (MODE == 0 && col0 < 1024) {
        // ---- LDS-transpose epilogue for Q and K stripes ----
        // stage acc+bias into smem tile [128 rows][128 cols] bf16, swizzled
#pragma unroll
        for (int mi = 0; mi < 4; ++mi)
#pragma unroll
            for (int nj = 0; nj < 4; ++nj) {
                const int coll = (wc << 6) + (nj << 4) + subcol;
                const float bi = bias[col0 + coll];
#pragma unroll
                for (int r = 0; r < 4; ++r) {
                    const int rowl = (wr << 6) + (mi << 4) + subrow + r;
                    *(bf16*)(smem + (rowl << 8) + (((coll << 1)) ^ ((rowl & 7) << 4))) =
                        (bf16)(acc[mi][nj][r] + bi);
                }
            }
        __syncthreads();
        const int trow = tid >> 1, thalf = tid & 1;
        const int rg = row0 + trow;
        const int bb2 = rg >> 12, n = rg & 4095;
        const char* src = smem + (trow << 8);
        const int sxor = (trow & 7) << 4;
        if (col0 < 512) {
            const int hh = (col0 >> 6) + thalf;
            char* dst = (char*)outQ + (((size_t)(bb2 * 8 + hh) * 4096 + n) << 7);
#pragma unroll
            for (int j = 0; j < 8; ++j)
                *(bf16x8*)(dst + (j << 4)) =
                    *(const bf16x8*)(src + (((thalf << 7) + (j << 4)) ^ sxor));
        } else {
            const int hh = ((col0 - 512) >> 6) + thalf;
            char* dst = (char*)outK + (size_t)rg * 1024 + hh * 128;
#pragma unroll
            for (int j = 0; j < 8; ++j)
                *(bf16x8*)(dst + ((j << 4) ^ sxor)) =
                    *(const bf16x8*)(src + (((thalf << 7) + (j << 4)) ^ sxor));
        }
        return;
    }

#pragma unroll
    for (int mi = 0; mi < 4; ++mi) {
#pragma unroll
        for (int nj = 0; nj < 4; ++nj) {
            const int cg = col0 + (wc << 6) + (nj << 4) + subcol;
            const float bi = bias[cg];
            const int rgb = row0 + (wr << 6) + (mi << 4) + subrow;
            if (MODE == 0) {
                // V stripe only (cg >= 1024)
                const int eg = cg - 1024, hh = eg >> 6, ee = eg & 63;
                const int bb2 = rgb >> 12, n = rgb & 4095;
                bf16x4 pv;
#pragma unroll
                for (int r = 0; r < 4; ++r) pv[r] = (bf16)(acc[mi][nj][r] + bi);
                const int nb = n * 2;
                size_t byteaddr = (size_t)((bb2 * 8 + hh) * 64 + ee) * 8192
                                + (size_t)((nb & ~127) | ((nb & 127) ^ ((ee & 7) << 4)));
                *(bf16x4*)((char*)outV + byteaddr) = pv;
            } else {
#pragma unroll
                for (int r = 0; r < 4; ++r) {
                    const int rg = rgb + r;
                    outF[(size_t)rg * 512 + cg] = acc[mi][nj][r] + bi + resid[(size_t)rg * 512 + cg];
                }
            }
        }
    }
}

// ---------------------------------------------------------------------------
// vsum+diag fused: block b (2048 blocks, 64 threads):
//   vsum[b] = sum_n Vt[b-th row][n]          (row = bh*64+e)
//   dgk[b*64+tid] = DIAG_C * sum_e K^2       (idx = bh*4096+n)
// ---------------------------------------------------------------------------
__global__ __launch_bounds__(64)
void vsum_diag_kernel(const bf16* __restrict__ Vt, const bf16* __restrict__ Kb,
                      float* __restrict__ vsum, float* __restrict__ dgk)
{
    const int row = blockIdx.x;
    const int tid = threadIdx.x;
    // ---- vsum part ----
    const bf16x8* p = (const bf16x8*)((const char*)Vt + (size_t)row * 8192);
    float s = 0.f;
#pragma unroll
    for (int i = 0; i < 8; ++i) {
        bf16x8 v = p[tid + i * 64];
#pragma unroll
        for (int u = 0; u < 8; ++u) s += (float)v[u];
    }
    s = warpReduceSum(s);
    if (tid == 0) vsum[row] = s;
    // ---- diag part ----
    const int idx = (row << 6) + tid;          // 0 .. 131071
    const int bh = idx >> 12, n = idx & 4095;
    const int b = bh >> 3, h = bh & 7;
    const char* krow = (const char*)Kb + (size_t)(b * 4096 + n) * 1024 + h * 128;
    const int sw = (n & 7) << 4;
    float ss = 0.f;
#pragma unroll
    for (int j = 0; j < 8; ++j) {
        bf16x8 v = *(const bf16x8*)(krow + ((j << 4) ^ sw));
#pragma unroll
        for (int u = 0; u < 8; ++u) { float f = (float)v[u]; ss += f * f; }
    }
    dgk[idx] = DIAG_C * ss;
}

// ---------------------------------------------------------------------------
// kside MFMA (round-6 structure + precomputed diag + NORM-folded projk +
// setprio around MFMA clusters): grid (32 bh, 8 m-tiles(64), 4 n-slices).
// Writes private f32 partials ctxp4[z], esumf4[z]; atomicMax gmax.
// ---------------------------------------------------------------------------
__global__ __launch_bounds__(256)
void kside_mfma2(const bf16* __restrict__ Kb, const bf16* __restrict__ Vt,
                 const float* __restrict__ projk, const float* __restrict__ dgk,
                 float* __restrict__ ctxp4, float* __restrict__ esumf4,
                 float* __restrict__ gmax)
{
    __shared__ char K_s[16384];
    __shared__ char V_s[16384];
    __shared__ char E_s[16384];
    __shared__ float part_s[4][64];
    __shared__ float wmax_s[4];

    const int tid = threadIdx.x;
    const int w = tid >> 6, l = tid & 63;
    const int bh = blockIdx.x;
    const int b = bh >> 3, h = bh & 7;
    const int m0 = blockIdx.y << 6;
    const int z = blockIdx.z;

    // projk fragments in regs, PRE-SCALED by NORMALIZER
    bf16x8 pk[4][2];
#pragma unroll
    for (int nj = 0; nj < 4; ++nj)
#pragma unroll
        for (int ks = 0; ks < 2; ++ks) {
            const int m = m0 + (nj << 4) + (l & 15);
            const int e0 = (ks << 5) + ((l >> 4) << 3);
            const float* p = projk + (size_t)m * 64 + e0;
            float4 a = *(const float4*)p;
            float4 c = *(const float4*)(p + 4);
            bf16x8 f;
            f[0] = (bf16)(NORMALIZER * a.x); f[1] = (bf16)(NORMALIZER * a.y);
            f[2] = (bf16)(NORMALIZER * a.z); f[3] = (bf16)(NORMALIZER * a.w);
            f[4] = (bf16)(NORMALIZER * c.x); f[5] = (bf16)(NORMALIZER * c.y);
            f[6] = (bf16)(NORMALIZER * c.z); f[7] = (bf16)(NORMALIZER * c.w);
            pk[nj][ks] = f;
        }

    const char* kg = (const char*)Kb + ((size_t)(b * 4096) * 512 + h * 64) * 2
                   + (size_t)((w << 3) + (l >> 3)) * 1024 + ((l & 7) << 4);
    const char* vg = (const char*)Vt + (size_t)bh * 64 * 8192
                   + (size_t)((w << 2) + (l >> 4)) * 8192 + ((l & 15) << 4);
    const float* dgb = dgk + (bh << 12) + (z << 10);

    float esacc[4] = {0.f, 0.f, 0.f, 0.f};
    float lmax = -1e30f;
    f32x4 acc2[4] = {};

    for (int c = 0; c < 8; ++c) {
        const int n0 = (z << 10) + (c << 7);
#pragma unroll
        for (int i = 0; i < 4; ++i) {
            gload16(kg + (size_t)(n0 + (i << 5)) * 1024, K_s + (i << 12) + (w << 10));
            gload16(vg + (size_t)(i << 4) * 8192 + (n0 << 1), V_s + (i << 12) + (w << 10));
        }
        __syncthreads();

        // E-phase: D[n][m] = K . (NORM*projk)^T
        f32x4 acc1[2][4] = {};
        __builtin_amdgcn_s_setprio(1);
#pragma unroll
        for (int ks = 0; ks < 2; ++ks) {
            bf16x8 af[2];
#pragma unroll
            for (int mi = 0; mi < 2; ++mi) {
                const int n = (w << 5) + (mi << 4) + (l & 15);
                const int addr = ((n << 7) + (ks << 6) + ((l >> 4) << 4)) ^ ((n & 7) << 4);
                af[mi] = *(const bf16x8*)(K_s + addr);
            }
#pragma unroll
            for (int mi = 0; mi < 2; ++mi)
#pragma unroll
                for (int nj = 0; nj < 4; ++nj)
                    acc1[mi][nj] = __builtin_amdgcn_mfma_f32_16x16x32_bf16(af[mi], pk[nj][ks], acc1[mi][nj], 0, 0, 0);
        }
        __builtin_amdgcn_s_setprio(0);
        // precomputed diag (f32x4 loads, L2-resident)
        float dgr[2][4];
#pragma unroll
        for (int mi = 0; mi < 2; ++mi) {
            float4 dv = *(const float4*)(dgb + (c << 7) + (w << 5) + (mi << 4) + ((l >> 4) << 2));
            dgr[mi][0] = dv.x; dgr[mi][1] = dv.y; dgr[mi][2] = dv.z; dgr[mi][3] = dv.w;
        }
        // exp -> E_s (bf16 [m][n], swizzled); esacc; lmax
#pragma unroll
        for (int mi = 0; mi < 2; ++mi) {
            const int nrow0 = (w << 5) + (mi << 4) + ((l >> 4) << 2);
#pragma unroll
            for (int nj = 0; nj < 4; ++nj) {
                const int m = (nj << 4) + (l & 15);
                bf16x4 ev;
#pragma unroll
                for (int r = 0; r < 4; ++r) {
                    const float d = acc1[mi][nj][r];      // = NORM*kdash
                    lmax = fmaxf(lmax, d);
                    const float e = __expf(d - dgr[mi][r]);
                    esacc[nj] += e;
                    ev[r] = (bf16)e;
                }
                const int addr = ((m << 8) + (nrow0 << 1)) ^ ((m & 7) << 4);
                *(bf16x4*)(E_s + addr) = ev;
            }
        }
        __syncthreads();

        // ctx-phase: acc2[m][e] += E^T . V
        __builtin_amdgcn_s_setprio(1);
#pragma unroll
        for (int ks = 0; ks < 4; ++ks) {
            const int mrow = (w << 4) + (l & 15);
            const int aaddr = ((mrow << 8) + (ks << 6) + ((l >> 4) << 4)) ^ ((mrow & 7) << 4);
            bf16x8 aE = *(const bf16x8*)(E_s + aaddr);
#pragma unroll
            for (int ej = 0; ej < 4; ++ej) {
                const int e = (ej << 4) + (l & 15);
                const int vaddr = ((e << 8) + (ks << 6) + ((l >> 4) << 4)) ^ ((e & 7) << 4);
                bf16x8 bV = *(const bf16x8*)(V_s + vaddr);
                acc2[ej] = __builtin_amdgcn_mfma_f32_16x16x32_bf16(aE, bV, acc2[ej], 0, 0, 0);
            }
        }
        __builtin_amdgcn_s_setprio(0);
        __syncthreads();
    }

#pragma unroll
    for (int nj = 0; nj < 4; ++nj) {
        float s = esacc[nj];
        s += __shfl_xor(s, 16); s += __shfl_xor(s, 32);
        if (l < 16) part_s[w][(nj << 4) + l] = s;
    }
#pragma unroll
    for (int off = 32; off > 0; off >>= 1) lmax = fmaxf(lmax, __shfl_xor(lmax, off));
    if (l == 0) wmax_s[w] = lmax;
    __syncthreads();
    if (tid < 64) {
        float es = part_s[0][tid] + part_s[1][tid] + part_s[2][tid] + part_s[3][tid];
        esumf4[((size_t)z * 32 + bh) * 512 + m0 + tid] = es;
        if (tid == 0)
            atomicMaxF(gmax, fmaxf(fmaxf(wmax_s[0], wmax_s[1]), fmaxf(wmax_s[2], wmax_s[3])));
    }
    const size_t zbase = (size_t)z * (32 * 512 * 64);
    const int mrow0 = m0 + (w << 4) + ((l >> 4) << 2);
#pragma unroll
    for (int ej = 0; ej < 4; ++ej) {
        const int e = (ej << 4) + (l & 15);
#pragma unroll
        for (int r = 0; r < 4; ++r)
            ctxp4[zbase + ((size_t)(bh * 512 + mrow0 + r)) * 64 + e] = acc2[ej][r];
    }
}

// ---------------------------------------------------------------------------
// finalize: sum 4 partials -> ctxE bf16 [bh][80][1024B rows, PRE-SWIZZLED
// byte ^= (e&7)<<4]; rows 64=ones, 65=esum; ctxsum (atomic); esumsum.
// Grid (32 bh, 4 m-chunks), block 256.
// ---------------------------------------------------------------------------
__global__ __launch_bounds__(256)
void finalize_ctx(const float* __restrict__ ctxp4, const float* __restrict__ esumf4,
                  bf16* __restrict__ ctxE, float* __restrict__ ctxsum,
                  float* __restrict__ esumsum)
{
    __shared__ float red_s[4][64];
    const int tid = threadIdx.x;
    const int bh = blockIdx.x;
    const int m0 = blockIdx.y << 7;
    const int e = tid & 63, ms = tid >> 6;
    const size_t Z = (size_t)32 * 512 * 64;

    const float* cb = ctxp4 + ((size_t)bh * 512 + m0 + ms * 32) * 64 + e;
    char* obr = (char*)ctxE + ((size_t)bh * 80 + e) * 1024;
    float s = 0.f;
#pragma unroll
    for (int i8 = 0; i8 < 4; ++i8) {
        bf16x8 pk8;
#pragma unroll
        for (int u = 0; u < 8; ++u) {
            const size_t off = (size_t)(i8 * 8 + u) * 64;
            float v = cb[off] + cb[off + Z] + cb[off + 2 * Z] + cb[off + 3 * Z];
            s += v;
            pk8[u] = (bf16)v;
        }
        const int inrow = ((m0 + ms * 32 + i8 * 8) << 1) ^ ((e & 7) << 4);
        *(bf16x8*)(obr + inrow) = pk8;
    }
    red_s[ms][e] = s;
    __syncthreads();
    if (tid < 64)
        atomicAdd(ctxsum + bh * 64 + tid,
                  red_s[0][tid] + red_s[1][tid] + red_s[2][tid] + red_s[3][tid]);
    if (tid < 128) {
        const int m = m0 + tid;
        float ev = esumf4[(size_t)bh * 512 + m]
                 + esumf4[((size_t)32 + bh) * 512 + m]
                 + esumf4[((size_t)64 + bh) * 512 + m]
                 + esumf4[((size_t)96 + bh) * 512 + m];
        bf16* er = ctxE + (size_t)(bh * 80 + 64) * 512;
        er[m] = (bf16)1.0f;                 // row 64 (e&7==0: no swizzle)
        er[512 + (m ^ 8)] = (bf16)ev;       // row 65: byte (m*2)^16 => elem m^8
        float t = warpReduceSum(ev);
        if ((tid & 63) == 0) atomicAdd(esumsum + bh, t);
    }
}

// ---------------------------------------------------------------------------
// q-side v4: 512 threads (8 waves), 512 q-rows/block, grid (32 bh, 8).
// LDS: ctxE fully staged (80KB, swizzled), Pq double-buffered (2x16KB,
// swizzled), T per-wave slab buffer (stride-80B rows). q in registers.
// ---------------------------------------------------------------------------
__global__ __launch_bounds__(512, 1)
void qside_mfma4(const bf16* __restrict__ Qb, const bf16* __restrict__ Pq,
                 const bf16* __restrict__ CtxE, const float* __restrict__ vsum,
                 const float* __restrict__ ctxsum, const float* __restrict__ esumsum,
                 const float* __restrict__ gmax, bf16* __restrict__ OutC)
{
    __shared__ char ctx_s[81920];        // [80 e][1024B] swizzled
    __shared__ char pq_s[2][16384];      // [128 feat][128B] swizzled
    __shared__ char T_s[40960];          // 8 waves x 64 rows x 80B

    const int tid = threadIdx.x;
    const int w = tid >> 6, l = tid & 63;
    const int lq = l & 15, lg = l >> 4;
    const int bh = blockIdx.x;
    const int b = bh >> 3, h = bh & 7;
    const int n0 = blockIdx.y << 9;

    // ---- prologue staging ----
    const char* ctxg = (const char*)CtxE + (size_t)bh * 81920;
    const char* pqg  = (const char*)Pq;
#pragma unroll
    for (int i = 0; i < 10; ++i)
        gload16(ctxg + (i << 13) + (tid << 4), ctx_s + (i << 13) + (w << 10));
#pragma unroll
    for (int p = 0; p < 2; ++p)
        gload16(pqg + (p << 13) + (tid << 4), pq_s[0] + (p << 13) + (w << 10));

    // q fragments (B-operand) + per-lane diag (col n = ni*16+lq)
    const char* qgb = (const char*)Qb + ((size_t)bh * 4096 + n0 + (w << 6)) * 128;
    bf16x8 qa[4][2];
    float diag_l[4];
#pragma unroll
    for (int ni = 0; ni < 4; ++ni) {
        const char* qr = qgb + ((ni << 4) + lq) * 128;
        float ss = 0.f;
#pragma unroll
        for (int kk = 0; kk < 2; ++kk) {
            qa[ni][kk] = *(const bf16x8*)(qr + (kk << 6) + (lg << 4));
#pragma unroll
            for (int u = 0; u < 8; ++u) { float f = (float)qa[ni][kk][u]; ss += f * f; }
        }
        ss += __shfl_xor(ss, 16);
        ss += __shfl_xor(ss, 32);
        diag_l[ni] = DIAG_C * ss;
    }

    f32x4 acc2[4][5] = {};
    float mmax[4] = {-1e30f, -1e30f, -1e30f, -1e30f};
    char* tw = T_s + w * 5120;
    const f32x4 Zc = {0.f, 0.f, 0.f, 0.f};

    __syncthreads();

    for (int ft = 0; ft < 4; ++ft) {
        const int buf = ft & 1;
        if (ft < 3) {
#pragma unroll
            for (int p = 0; p < 2; ++p)
                gload16(pqg + ((ft + 1) << 14) + (p << 13) + (tid << 4),
                        pq_s[buf ^ 1] + (p << 13) + (w << 10));
        }
        const char* pqb = pq_s[buf];
#pragma unroll
        for (int sl = 0; sl < 4; ++sl) {
            // ---- phase 1: D[m][n] = projq . q^T, K=64, 32 m's ----
            f32x4 acc1[2][4];
#pragma unroll
            for (int mi = 0; mi < 2; ++mi) {
                const int fr = (sl << 5) + (mi << 4) + lq;
                bf16x8 pf = *(const bf16x8*)(pqb + fr * 128 +
                              (((lg << 4)) ^ ((lq & 7) << 4)));
#pragma unroll
                for (int ni = 0; ni < 4; ++ni)
                    acc1[mi][ni] = __builtin_amdgcn_mfma_f32_16x16x32_bf16(pf, qa[ni][0], Zc, 0, 0, 0);
            }
#pragma unroll
            for (int mi = 0; mi < 2; ++mi) {
                const int fr = (sl << 5) + (mi << 4) + lq;
                bf16x8 pf = *(const bf16x8*)(pqb + fr * 128 +
                              ((64 + (lg << 4)) ^ ((lq & 7) << 4)));
#pragma unroll
                for (int ni = 0; ni < 4; ++ni)
                    acc1[mi][ni] = __builtin_amdgcn_mfma_f32_16x16x32_bf16(pf, qa[ni][1], acc1[mi][ni], 0, 0, 0);
            }
            // ---- exp -> wave-private T_s slab ----
#pragma unroll
            for (int mi = 0; mi < 2; ++mi)
#pragma unroll
                for (int ni = 0; ni < 4; ++ni) {
                    bf16x4 tv;
#pragma unroll
                    for (int r = 0; r < 4; ++r) {
                        const float qd = acc1[mi][ni][r];
                        mmax[ni] = fmaxf(mmax[ni], qd);
                        tv[r] = (bf16)__expf(NORMALIZER * qd - diag_l[ni]);
                    }
                    *(bf16x4*)(tw + ((ni << 4) + lq) * 80 + (mi << 5) + (lg << 3)) = tv;
                }
            // ---- phase 2: acc2 += T . ctxE^T (32-k slab) ----
            bf16x8 ta[4];
#pragma unroll
            for (int ni = 0; ni < 4; ++ni)
                ta[ni] = *(const bf16x8*)(tw + ((ni << 4) + lq) * 80 + (lg << 4));
#pragma unroll
            for (int nj = 0; nj < 5; ++nj) {
                const int e = (nj << 4) + lq;
                bf16x8 cb = *(const bf16x8*)(ctx_s + e * 1024 +
                              (((ft << 8) + (sl << 6) + (lg << 4)) ^ ((e & 7) << 4)));
#pragma unroll
                for (int ni = 0; ni < 4; ++ni)
                    acc2[ni][nj] = __builtin_amdgcn_mfma_f32_16x16x32_bf16(ta[ni], cb, acc2[ni][nj], 0, 0, 0);
            }
        }
        __syncthreads();
    }

    // ---- epilogue: uT=col64, uE=col65 ----
    const float sG = __expf(-gmax[0]);
    const float ess = esumsum[bh];
    bf16* outb = OutC + ((size_t)(b * 4096) + n0 + (w << 6)) * 512 + (h << 6);
#pragma unroll
    for (int ni = 0; ni < 4; ++ni) {
        float mmr = mmax[ni];
        mmr = fmaxf(mmr, __shfl_xor(mmr, 16));
        mmr = fmaxf(mmr, __shfl_xor(mmr, 32));
#pragma unroll
        for (int r = 0; r < 4; ++r) {
            const float mm = __shfl(mmr, (lg << 2) + r);
            const float uT = __shfl(acc2[ni][4][r], (lg << 4));
            const float uE = __shfl(acc2[ni][4][r], (lg << 4) | 1);
            const float cr = __expf(-NORMALIZER * mm);
            const float qsum = cr * uT + KEPS * 512.0f;
            const float D = sG * (cr * uE + KEPS * ess) + KEPS * 4096.0f * qsum;
            const float inv = 1.0f / D;
            const float al = sG * cr * inv;
            const float G1 = sG * KEPS * inv;
            const float G2 = KEPS * qsum * inv;
            const int row = (ni << 4) + (lg << 2) + r;
#pragma unroll
            for (int nj = 0; nj < 4; ++nj) {
                const int e = (nj << 4) + lq;
                float v = al * acc2[ni][nj][r] + G1 * ctxsum[(bh << 6) + e] + G2 * vsum[(bh << 6) + e];
                outb[(size_t)row * 512 + e] = (bf16)v;
            }
        }
    }
}

// ---------------------------------------------------------------------------
// LayerNorm over D=512, 4 rows per 256-thread block. Grid 4096.
// ---------------------------------------------------------------------------
__global__ __launch_bounds__(256)
void ln_kernel(const float* __restrict__ hid, const float* __restrict__ gamma,
               const float* __restrict__ beta, float* __restrict__ out)
{
    const int row = (blockIdx.x << 2) + (threadIdx.x >> 6);
    const int lane = threadIdx.x & 63;
    const float* x = hid + (size_t)row * DMODEL + (lane << 3);
    float4 a = *(const float4*)x;
    float4 c = *(const float4*)(x + 4);
    float s = a.x + a.y + a.z + a.w + c.x + c.y + c.z + c.w;
    float sq = a.x * a.x + a.y * a.y + a.z * a.z + a.w * a.w +
               c.x * c.x + c.y * c.y + c.z * c.z + c.w * c.w;
    s = warpReduceSum(s);
    sq = warpReduceSum(sq);
    const float mu = s * 0.001953125f;
    const float var = sq * 0.001953125f - mu * mu;
    const float rs = rsqrtf(var + 1e-12f);
    const float4 g1 = *(const float4*)(gamma + (lane << 3));
    const float4 g2 = *(const float4*)(gamma + (lane << 3) + 4);
    const float4 b1 = *(const float4*)(beta + (lane << 3));
    const float4 b2 = *(const float4*)(beta + (lane << 3) + 4);
    float4 o1, o2;
    o1.x = (a.x - mu) * rs * g1.x + b1.x;
    o1.y = (a.y - mu) * rs * g1.y + b1.y;
    o1.z = (a.z - mu) * rs * g1.z + b1.z;
    o1.w = (a.w - mu) * rs * g1.w + b1.w;
    o2.x = (c.x - mu) * rs * g2.x + b2.x;
    o2.y = (c.y - mu) * rs * g2.y + b2.y;
    o2.z = (c.z - mu) * rs * g2.z + b2.z;
    o2.w = (c.w - mu) * rs * g2.w + b2.w;
    *(float4*)(out + (size_t)row * DMODEL + (lane << 3)) = o1;
    *(float4*)(out + (size_t)row * DMODEL + (lane << 3) + 4) = o2;
}

__global__ void init_misc(float* gmax)
{
    if (threadIdx.x == 0 && blockIdx.x == 0) *gmax = -1e30f;
}

// ---------------------------------------------------------------------------
extern "C" void kernel_launch(void* const* d_in, const int* in_sizes, int n_in,
                              void* d_out, int out_size, void* d_ws, size_t ws_size,
                              hipStream_t stream)
{
    const float* x     = (const float*)d_in[0];
    const float* Wq    = (const float*)d_in[2];
    const float* bq    = (const float*)d_in[3];
    const float* Wk    = (const float*)d_in[4];
    const float* bk    = (const float*)d_in[5];
    const float* Wv    = (const float*)d_in[6];
    const float* bv    = (const float*)d_in[7];
    const float* projq = (const float*)d_in[8];
    const float* projk = (const float*)d_in[9];
    const float* Wd    = (const float*)d_in[10];
    const float* bd    = (const float*)d_in[11];
    const float* gamma = (const float*)d_in[12];
    const float* beta  = (const float*)d_in[13];

    char* W = (char*)d_ws;
    bf16*  qb16   = (bf16*) (W);                   // 16 MB  [bh][n][64]
    bf16*  kb16s  = (bf16*) (W + 16777216);        // 16 MB (swizzled rows)
    bf16*  vtb    = (bf16*) (W + 33554432);        // 16 MB (transposed+swizzled)
    bf16*  xb16   = (bf16*) (W + 50331648);        // 16 MB (x bf16, later ctx bf16)
    float* hidf32 = (float*)(W + 67108864);        // 32 MB (aliases ctxp4/esumf4/dgk)
    float* ctxp4  = (float*)(W + 67108864);        // 16 MB  [4][32][512][64] f32
    float* esumf4 = (float*)(W + 83886080);        // 256 KB [4][32][512] f32
    float* dgk    = (float*)(W + 84148224);        // 512 KB [32][4096] f32
    bf16*  Wb16   = (bf16*) (W + 100663296);       // 1.5 MB
    bf16*  Wdb16  = (bf16*) (W + 102236160);       // 0.5 MB
    bf16*  pqb16  = (bf16*) (W + 102760448);       // 64 KB (pre-swizzled)
    float* bcat   = (float*)(W + 102825984);       // 6 KB
    bf16*  ctxE   = (bf16*) (W + 102832128);       // 2,621,440 B [32][80][512] swz
    float* vsumb  = (float*)(W + 105453568);       // 8 KB
    float* ctxsum = (float*)(W + 105461760);       // 8 KB
    float* esmsm  = (float*)(W + 105469952);       // 128 B
    float* gmaxb  = (float*)(W + 105470080);       // 4 B

    prep_convert<<<9250, 256, 0, stream>>>(x, Wq, Wk, Wv, Wd, projq, bq, bk, bv,
                                           xb16, Wb16, Wdb16, pqb16, bcat);
    hipMemsetAsync(ctxE, 0, 2621440, stream);                  // zero rows 66-79
    hipMemsetAsync(ctxsum, 0, 8192 + 128, stream);             // ctxsum + esumsum
    init_misc<<<1, 64, 0, stream>>>(gmaxb);

    gemm_mfma<0><<<dim3(12, 128), 256, 0, stream>>>(xb16, Wb16, bcat, nullptr,
                                                    qb16, kb16s, vtb, nullptr);

    vsum_diag_kernel<<<2048, 64, 0, stream>>>(vtb, kb16s, vsumb, dgk);
    kside_mfma2<<<dim3(32, 8, 4), 256, 0, stream>>>(kb16s, vtb, projk, dgk,
                                                    ctxp4, esumf4, gmaxb);
    finalize_ctx<<<dim3(32, 4), 256, 0, stream>>>(ctxp4, esumf4, ctxE, ctxsum, esmsm);

    qside_mfma4<<<dim3(32, 8), 512, 0, stream>>>(qb16, pqb16, ctxE, vsumb,
                                                 ctxsum, esmsm, gmaxb, xb16);

    gemm_mfma<1><<<dim3(4, 128), 256, 0, stream>>>(xb16, Wdb16, bd, x,
                                                   nullptr, nullptr, nullptr, hidf32);
    ln_kernel<<<4096, 256, 0, stream>>>(hidf32, gamma, beta, (float*)d_out);
}

// Round 18
// 185.498 us; speedup vs baseline: 1.0475x; 1.0475x over previous
//
#include <hip/hip_runtime.h>
#include <math.h>

typedef __bf16 bf16;
typedef __bf16 bf16x8 __attribute__((ext_vector_type(8)));
typedef __bf16 bf16x4 __attribute__((ext_vector_type(4)));
typedef float  f32x4  __attribute__((ext_vector_type(4)));

#define NSEQ 4096
#define DMODEL 512
#define DHEAD 64
#define MFEAT 512
#define BHEADS 32
#define ROWS_TOTAL 16384

#define NORMALIZER 0.35355339059327373f
#define DIAG_C 0.0625f
#define KEPS 1e-4f

__device__ __forceinline__ float warpReduceSum(float v) {
#pragma unroll
    for (int off = 32; off > 0; off >>= 1) v += __shfl_xor(v, off);
    return v;
}

__device__ __forceinline__ void atomicMaxF(float* addr, float val) {
    int* ai = (int*)addr;
    int cur = __float_as_int(*addr);
    while (__int_as_float(cur) < val) {
        int prev = atomicCAS(ai, cur, __float_as_int(val));
        if (prev == cur) break;
        cur = prev;
    }
}

__device__ __forceinline__ void gload16(const void* g, void* l) {
    __builtin_amdgcn_global_load_lds((const __attribute__((address_space(1))) void*)g,
                                     (__attribute__((address_space(3))) void*)l, 16, 0, 0);
}

// ---------------------------------------------------------------------------
// prep: f32 -> bf16 conversions + weight concat + bias concat.
// pqb written PRE-SWIZZLED per 128B row: byte ^= (feat&7)<<4.
// Tail threads (e0 >= 9471488, 128 of them) zero ctxsum/esumsum + init gmax.
// ---------------------------------------------------------------------------
__global__ __launch_bounds__(256)
void prep_convert(const float* __restrict__ x, const float* __restrict__ Wq,
                  const float* __restrict__ Wk, const float* __restrict__ Wv,
                  const float* __restrict__ Wd, const float* __restrict__ pq,
                  const float* __restrict__ bq, const float* __restrict__ bk,
                  const float* __restrict__ bv,
                  bf16* __restrict__ xb, bf16* __restrict__ Wb,
                  bf16* __restrict__ Wdb, bf16* __restrict__ pqb,
                  float* __restrict__ bcat, float* __restrict__ ctxsum,
                  float* __restrict__ esumsum, float* __restrict__ gmax)
{
    size_t i4 = (size_t)blockIdx.x * 256 + threadIdx.x;
    size_t e0 = i4 * 4;
    if (e0 >= 9471488) {
        const int t = (int)(i4 - 2367872);      // 0..127
        float4 z = {0.f, 0.f, 0.f, 0.f};
#pragma unroll
        for (int j = 0; j < 4; ++j)
            *(float4*)(ctxsum + (t << 4) + (j << 2)) = z;
        if (t < 32) esumsum[t] = 0.f;
        if (t == 0) *gmax = -1e30f;
        return;
    }
    const float* src;
    if (e0 < 8388608) {
        src = x + e0;
        float4 v = *(const float4*)src;
        bf16* d = xb + e0;
        d[0] = (bf16)v.x; d[1] = (bf16)v.y; d[2] = (bf16)v.z; d[3] = (bf16)v.w;
    } else if (e0 < 9175040) {
        size_t c = e0 - 8388608; int wsel = (int)(c >> 18); size_t o = c & 262143;
        src = (wsel == 0 ? Wq : wsel == 1 ? Wk : Wv) + o;
        float4 v = *(const float4*)src;
        bf16* d = Wb + c;
        d[0] = (bf16)v.x; d[1] = (bf16)v.y; d[2] = (bf16)v.z; d[3] = (bf16)v.w;
    } else if (e0 < 9437184) {
        size_t c = e0 - 9175040;
        src = Wd + c;
        float4 v = *(const float4*)src;
        bf16* d = Wdb + c;
        d[0] = (bf16)v.x; d[1] = (bf16)v.y; d[2] = (bf16)v.z; d[3] = (bf16)v.w;
    } else if (e0 < 9469952) {
        size_t c = e0 - 9437184;           // multiple of 4
        src = pq + c;
        float4 v = *(const float4*)src;
        const int feat = (int)(c >> 6), col = (int)(c & 63);
        bf16x4 d4;
        d4[0] = (bf16)v.x; d4[1] = (bf16)v.y; d4[2] = (bf16)v.z; d4[3] = (bf16)v.w;
        const int inrow = (col << 1) ^ ((feat & 7) << 4);
        *(bf16x4*)((char*)pqb + (size_t)feat * 128 + inrow) = d4;
    } else {
        size_t c = e0 - 9469952; int wsel = (int)(c >> 9); size_t o = c & 511;
        src = (wsel == 0 ? bq : wsel == 1 ? bk : bv) + o;
        *(float4*)(bcat + c) = *(const float4*)src;
    }
}

// ---------------------------------------------------------------------------
// bf16 MFMA GEMM, C = A * B^T (+bias)(+resid), 128x128 tile, BK=64.
// MODE 0: A=xb16, B=Wcat[1536x512]; Q->bf16 [bh][n][64]; K->bf16 swizzled rows;
//         V->bf16 transposed [bh][e][n] swizzled.
//         Q/K stripes: LDS-transpose epilogue (vectorized stores).
// MODE 1: A=ctxb16, B=Wd; hid(bf16, via outQ ptr) = +bias +resid
// ---------------------------------------------------------------------------
template<int MODE>
__global__ __launch_bounds__(256)
void gemm_mfma(const bf16* __restrict__ A, const bf16* __restrict__ Bw,
               const float* __restrict__ bias, const float* __restrict__ resid,
               bf16* __restrict__ outQ, bf16* __restrict__ outK,
               bf16* __restrict__ outV)
{
    __shared__ char smem[32768];
    char* As = smem;
    char* Bs = smem + 16384;
    const int tid = threadIdx.x;
    const int w = tid >> 6, l = tid & 63;
    const int wr = w >> 1, wc = w & 1;
    const int row0 = blockIdx.y << 7;
    const int col0 = blockIdx.x << 7;

    f32x4 acc[4][4] = {};
    const char* Ab = (const char*)A + (size_t)row0 * 1024;
    const char* Bb = (const char*)Bw + (size_t)col0 * 1024;

    for (int kt = 0; kt < 8; ++kt) {
        const int k0b = kt << 7;
#pragma unroll
        for (int i = 0; i < 4; ++i) {
            int off = (i << 12) + (tid << 4);
            int g = off ^ ((off >> 3) & 0x70);
            int grow = g >> 7, gcol = g & 127;
            gload16(Ab + (size_t)grow * 1024 + k0b + gcol, As + (i << 12) + (w << 10));
            gload16(Bb + (size_t)grow * 1024 + k0b + gcol, Bs + (i << 12) + (w << 10));
        }
        __syncthreads();
#pragma unroll
        for (int ks = 0; ks < 2; ++ks) {
            bf16x8 af[4], bb[4];
#pragma unroll
            for (int mi = 0; mi < 4; ++mi) {
                int row = (wr << 6) + (mi << 4) + (l & 15);
                int addr = ((row << 7) + (ks << 6) + ((l >> 4) << 4)) ^ ((row & 7) << 4);
                af[mi] = *(const bf16x8*)(As + addr);
            }
#pragma unroll
            for (int nj = 0; nj < 4; ++nj) {
                int row = (wc << 6) + (nj << 4) + (l & 15);
                int addr = ((row << 7) + (ks << 6) + ((l >> 4) << 4)) ^ ((row & 7) << 4);
                bb[nj] = *(const bf16x8*)(Bs + addr);
            }
#pragma unroll
            for (int mi = 0; mi < 4; ++mi)
#pragma unroll
                for (int nj = 0; nj < 4; ++nj)
                    acc[mi][nj] = __builtin_amdgcn_mfma_f32_16x16x32_bf16(af[mi], bb[nj], acc[mi][nj], 0, 0, 0);
        }
        __syncthreads();
    }

    const int subrow = (l >> 4) << 2;
    const int subcol = l & 15;

    if (MODE == 0 && col0 < 1024) {
        // ---- LDS-transpose epilogue for Q and K stripes ----
#pragma unroll
        for (int mi = 0; mi < 4; ++mi)
#pragma unroll
            for (int nj = 0; nj < 4; ++nj) {
                const int coll = (wc << 6) + (nj << 4) + subcol;
                const float bi = bias[col0 + coll];
#pragma unroll
                for (int r = 0; r < 4; ++r) {
                    const int rowl = (wr << 6) + (mi << 4) + subrow + r;
                    *(bf16*)(smem + (rowl << 8) + (((coll << 1)) ^ ((rowl & 7) << 4))) =
                        (bf16)(acc[mi][nj][r] + bi);
                }
            }
        __syncthreads();
        const int trow = tid >> 1, thalf = tid & 1;
        const int rg = row0 + trow;
        const int bb2 = rg >> 12, n = rg & 4095;
        const char* src = smem + (trow << 8);
        const int sxor = (trow & 7) << 4;
        if (col0 < 512) {
            const int hh = (col0 >> 6) + thalf;
            char* dst = (char*)outQ + (((size_t)(bb2 * 8 + hh) * 4096 + n) << 7);
#pragma unroll
            for (int j = 0; j < 8; ++j)
                *(bf16x8*)(dst + (j << 4)) =
                    *(const bf16x8*)(src + (((thalf << 7) + (j << 4)) ^ sxor));
        } else {
            const int hh = ((col0 - 512) >> 6) + thalf;
            char* dst = (char*)outK + (size_t)rg * 1024 + hh * 128;
#pragma unroll
            for (int j = 0; j < 8; ++j)
                *(bf16x8*)(dst + ((j << 4) ^ sxor)) =
                    *(const bf16x8*)(src + (((thalf << 7) + (j << 4)) ^ sxor));
        }
        return;
    }

#pragma unroll
    for (int mi = 0; mi < 4; ++mi) {
#pragma unroll
        for (int nj = 0; nj < 4; ++nj) {
            const int cg = col0 + (wc << 6) + (nj << 4) + subcol;
            const float bi = bias[cg];
            const int rgb = row0 + (wr << 6) + (mi << 4) + subrow;
            if (MODE == 0) {
                // V stripe only (cg >= 1024)
                const int eg = cg - 1024, hh = eg >> 6, ee = eg & 63;
                const int bb2 = rgb >> 12, n = rgb & 4095;
                bf16x4 pv;
#pragma unroll
                for (int r = 0; r < 4; ++r) pv[r] = (bf16)(acc[mi][nj][r] + bi);
                const int nb = n * 2;
                size_t byteaddr = (size_t)((bb2 * 8 + hh) * 64 + ee) * 8192
                                + (size_t)((nb & ~127) | ((nb & 127) ^ ((ee & 7) << 4)));
                *(bf16x4*)((char*)outV + byteaddr) = pv;
            } else {
                // hid (bf16) via outQ pointer
#pragma unroll
                for (int r = 0; r < 4; ++r) {
                    const int rg = rgb + r;
                    outQ[(size_t)rg * 512 + cg] =
                        (bf16)(acc[mi][nj][r] + bi + resid[(size_t)rg * 512 + cg]);
                }
            }
        }
    }
}

// ---------------------------------------------------------------------------
// vsum+diag fused: block b (2048 blocks, 64 threads).
// ---------------------------------------------------------------------------
__global__ __launch_bounds__(64)
void vsum_diag_kernel(const bf16* __restrict__ Vt, const bf16* __restrict__ Kb,
                      float* __restrict__ vsum, float* __restrict__ dgk)
{
    const int row = blockIdx.x;
    const int tid = threadIdx.x;
    const bf16x8* p = (const bf16x8*)((const char*)Vt + (size_t)row * 8192);
    float s = 0.f;
#pragma unroll
    for (int i = 0; i < 8; ++i) {
        bf16x8 v = p[tid + i * 64];
#pragma unroll
        for (int u = 0; u < 8; ++u) s += (float)v[u];
    }
    s = warpReduceSum(s);
    if (tid == 0) vsum[row] = s;
    const int idx = (row << 6) + tid;
    const int bh = idx >> 12, n = idx & 4095;
    const int b = bh >> 3, h = bh & 7;
    const char* krow = (const char*)Kb + (size_t)(b * 4096 + n) * 1024 + h * 128;
    const int sw = (n & 7) << 4;
    float ss = 0.f;
#pragma unroll
    for (int j = 0; j < 8; ++j) {
        bf16x8 v = *(const bf16x8*)(krow + ((j << 4) ^ sw));
#pragma unroll
        for (int u = 0; u < 8; ++u) { float f = (float)v[u]; ss += f * f; }
    }
    dgk[idx] = DIAG_C * ss;
}

// ---------------------------------------------------------------------------
// kside MFMA: grid (32 bh, 8 m-tiles(64), 4 n-slices), block 256.
// ---------------------------------------------------------------------------
__global__ __launch_bounds__(256)
void kside_mfma2(const bf16* __restrict__ Kb, const bf16* __restrict__ Vt,
                 const float* __restrict__ projk, const float* __restrict__ dgk,
                 float* __restrict__ ctxp4, float* __restrict__ esumf4,
                 float* __restrict__ gmax)
{
    __shared__ char K_s[16384];
    __shared__ char V_s[16384];
    __shared__ char E_s[16384];
    __shared__ float part_s[4][64];
    __shared__ float wmax_s[4];

    const int tid = threadIdx.x;
    const int w = tid >> 6, l = tid & 63;
    const int bh = blockIdx.x;
    const int b = bh >> 3, h = bh & 7;
    const int m0 = blockIdx.y << 6;
    const int z = blockIdx.z;

    bf16x8 pk[4][2];
#pragma unroll
    for (int nj = 0; nj < 4; ++nj)
#pragma unroll
        for (int ks = 0; ks < 2; ++ks) {
            const int m = m0 + (nj << 4) + (l & 15);
            const int e0 = (ks << 5) + ((l >> 4) << 3);
            const float* p = projk + (size_t)m * 64 + e0;
            float4 a = *(const float4*)p;
            float4 c = *(const float4*)(p + 4);
            bf16x8 f;
            f[0] = (bf16)(NORMALIZER * a.x); f[1] = (bf16)(NORMALIZER * a.y);
            f[2] = (bf16)(NORMALIZER * a.z); f[3] = (bf16)(NORMALIZER * a.w);
            f[4] = (bf16)(NORMALIZER * c.x); f[5] = (bf16)(NORMALIZER * c.y);
            f[6] = (bf16)(NORMALIZER * c.z); f[7] = (bf16)(NORMALIZER * c.w);
            pk[nj][ks] = f;
        }

    const char* kg = (const char*)Kb + ((size_t)(b * 4096) * 512 + h * 64) * 2
                   + (size_t)((w << 3) + (l >> 3)) * 1024 + ((l & 7) << 4);
    const char* vg = (const char*)Vt + (size_t)bh * 64 * 8192
                   + (size_t)((w << 2) + (l >> 4)) * 8192 + ((l & 15) << 4);
    const float* dgb = dgk + (bh << 12) + (z << 10);

    float esacc[4] = {0.f, 0.f, 0.f, 0.f};
    float lmax = -1e30f;
    f32x4 acc2[4] = {};

    for (int c = 0; c < 8; ++c) {
        const int n0 = (z << 10) + (c << 7);
#pragma unroll
        for (int i = 0; i < 4; ++i) {
            gload16(kg + (size_t)(n0 + (i << 5)) * 1024, K_s + (i << 12) + (w << 10));
            gload16(vg + (size_t)(i << 4) * 8192 + (n0 << 1), V_s + (i << 12) + (w << 10));
        }
        __syncthreads();

        f32x4 acc1[2][4] = {};
        __builtin_amdgcn_s_setprio(1);
#pragma unroll
        for (int ks = 0; ks < 2; ++ks) {
            bf16x8 af[2];
#pragma unroll
            for (int mi = 0; mi < 2; ++mi) {
                const int n = (w << 5) + (mi << 4) + (l & 15);
                const int addr = ((n << 7) + (ks << 6) + ((l >> 4) << 4)) ^ ((n & 7) << 4);
                af[mi] = *(const bf16x8*)(K_s + addr);
            }
#pragma unroll
            for (int mi = 0; mi < 2; ++mi)
#pragma unroll
                for (int nj = 0; nj < 4; ++nj)
                    acc1[mi][nj] = __builtin_amdgcn_mfma_f32_16x16x32_bf16(af[mi], pk[nj][ks], acc1[mi][nj], 0, 0, 0);
        }
        __builtin_amdgcn_s_setprio(0);
        float dgr[2][4];
#pragma unroll
        for (int mi = 0; mi < 2; ++mi) {
            float4 dv = *(const float4*)(dgb + (c << 7) + (w << 5) + (mi << 4) + ((l >> 4) << 2));
            dgr[mi][0] = dv.x; dgr[mi][1] = dv.y; dgr[mi][2] = dv.z; dgr[mi][3] = dv.w;
        }
#pragma unroll
        for (int mi = 0; mi < 2; ++mi) {
            const int nrow0 = (w << 5) + (mi << 4) + ((l >> 4) << 2);
#pragma unroll
            for (int nj = 0; nj < 4; ++nj) {
                const int m = (nj << 4) + (l & 15);
                bf16x4 ev;
#pragma unroll
                for (int r = 0; r < 4; ++r) {
                    const float d = acc1[mi][nj][r];
                    lmax = fmaxf(lmax, d);
                    const float e = __expf(d - dgr[mi][r]);
                    esacc[nj] += e;
                    ev[r] = (bf16)e;
                }
                const int addr = ((m << 8) + (nrow0 << 1)) ^ ((m & 7) << 4);
                *(bf16x4*)(E_s + addr) = ev;
            }
        }
        __syncthreads();

        __builtin_amdgcn_s_setprio(1);
#pragma unroll
        for (int ks = 0; ks < 4; ++ks) {
            const int mrow = (w << 4) + (l & 15);
            const int aaddr = ((mrow << 8) + (ks << 6) + ((l >> 4) << 4)) ^ ((mrow & 7) << 4);
            bf16x8 aE = *(const bf16x8*)(E_s + aaddr);
#pragma unroll
            for (int ej = 0; ej < 4; ++ej) {
                const int e = (ej << 4) + (l & 15);
                const int vaddr = ((e << 8) + (ks << 6) + ((l >> 4) << 4)) ^ ((e & 7) << 4);
                bf16x8 bV = *(const bf16x8*)(V_s + vaddr);
                acc2[ej] = __builtin_amdgcn_mfma_f32_16x16x32_bf16(aE, bV, acc2[ej], 0, 0, 0);
            }
        }
        __builtin_amdgcn_s_setprio(0);
        __syncthreads();
    }

#pragma unroll
    for (int nj = 0; nj < 4; ++nj) {
        float s = esacc[nj];
        s += __shfl_xor(s, 16); s += __shfl_xor(s, 32);
        if (l < 16) part_s[w][(nj << 4) + l] = s;
    }
#pragma unroll
    for (int off = 32; off > 0; off >>= 1) lmax = fmaxf(lmax, __shfl_xor(lmax, off));
    if (l == 0) wmax_s[w] = lmax;
    __syncthreads();
    if (tid < 64) {
        float es = part_s[0][tid] + part_s[1][tid] + part_s[2][tid] + part_s[3][tid];
        esumf4[((size_t)z * 32 + bh) * 512 + m0 + tid] = es;
        if (tid == 0)
            atomicMaxF(gmax, fmaxf(fmaxf(wmax_s[0], wmax_s[1]), fmaxf(wmax_s[2], wmax_s[3])));
    }
    const size_t zbase = (size_t)z * (32 * 512 * 64);
    const int mrow0 = m0 + (w << 4) + ((l >> 4) << 2);
#pragma unroll
    for (int ej = 0; ej < 4; ++ej) {
        const int e = (ej << 4) + (l & 15);
#pragma unroll
        for (int r = 0; r < 4; ++r)
            ctxp4[zbase + ((size_t)(bh * 512 + mrow0 + r)) * 64 + e] = acc2[ej][r];
    }
}

// ---------------------------------------------------------------------------
// finalize: sum 4 partials -> ctxE bf16 [bh][80][1024B rows, PRE-SWIZZLED
// byte ^= (e&7)<<4]; rows 64=ones, 65=esum; ctxsum (atomic); esumsum.
// Grid (32 bh, 4 m-chunks), block 256.
// ---------------------------------------------------------------------------
__global__ __launch_bounds__(256)
void finalize_ctx(const float* __restrict__ ctxp4, const float* __restrict__ esumf4,
                  bf16* __restrict__ ctxE, float* __restrict__ ctxsum,
                  float* __restrict__ esumsum)
{
    __shared__ float red_s[4][64];
    const int tid = threadIdx.x;
    const int bh = blockIdx.x;
    const int m0 = blockIdx.y << 7;
    const int e = tid & 63, ms = tid >> 6;
    const size_t Z = (size_t)32 * 512 * 64;

    const float* cb = ctxp4 + ((size_t)bh * 512 + m0 + ms * 32) * 64 + e;
    char* obr = (char*)ctxE + ((size_t)bh * 80 + e) * 1024;
    float s = 0.f;
#pragma unroll
    for (int i8 = 0; i8 < 4; ++i8) {
        bf16x8 pk8;
#pragma unroll
        for (int u = 0; u < 8; ++u) {
            const size_t off = (size_t)(i8 * 8 + u) * 64;
            float v = cb[off] + cb[off + Z] + cb[off + 2 * Z] + cb[off + 3 * Z];
            s += v;
            pk8[u] = (bf16)v;
        }
        const int inrow = ((m0 + ms * 32 + i8 * 8) << 1) ^ ((e & 7) << 4);
        *(bf16x8*)(obr + inrow) = pk8;
    }
    red_s[ms][e] = s;
    __syncthreads();
    if (tid < 64)
        atomicAdd(ctxsum + bh * 64 + tid,
                  red_s[0][tid] + red_s[1][tid] + red_s[2][tid] + red_s[3][tid]);
    if (tid < 128) {
        const int m = m0 + tid;
        float ev = esumf4[(size_t)bh * 512 + m]
                 + esumf4[((size_t)32 + bh) * 512 + m]
                 + esumf4[((size_t)64 + bh) * 512 + m]
                 + esumf4[((size_t)96 + bh) * 512 + m];
        bf16* er = ctxE + (size_t)(bh * 80 + 64) * 512;
        er[m] = (bf16)1.0f;                 // row 64 (e&7==0: no swizzle)
        er[512 + (m ^ 8)] = (bf16)ev;       // row 65: byte (m*2)^16 => elem m^8
        float t = warpReduceSum(ev);
        if ((tid & 63) == 0) atomicAdd(esumsum + bh, t);
    }
}

// ---------------------------------------------------------------------------
// q-side v4: 512 threads (8 waves), 512 q-rows/block, grid (32 bh, 8).
// ---------------------------------------------------------------------------
__global__ __launch_bounds__(512, 1)
void qside_mfma4(const bf16* __restrict__ Qb, const bf16* __restrict__ Pq,
                 const bf16* __restrict__ CtxE, const float* __restrict__ vsum,
                 const float* __restrict__ ctxsum, const float* __restrict__ esumsum,
                 const float* __restrict__ gmax, bf16* __restrict__ OutC)
{
    __shared__ char ctx_s[81920];        // [80 e][1024B] swizzled
    __shared__ char pq_s[2][16384];      // [128 feat][128B] swizzled
    __shared__ char T_s[40960];          // 8 waves x 64 rows x 80B

    const int tid = threadIdx.x;
    const int w = tid >> 6, l = tid & 63;
    const int lq = l & 15, lg = l >> 4;
    const int bh = blockIdx.x;
    const int b = bh >> 3, h = bh & 7;
    const int n0 = blockIdx.y << 9;

    const char* ctxg = (const char*)CtxE + (size_t)bh * 81920;
    const char* pqg  = (const char*)Pq;
#pragma unroll
    for (int i = 0; i < 10; ++i)
        gload16(ctxg + (i << 13) + (tid << 4), ctx_s + (i << 13) + (w << 10));
#pragma unroll
    for (int p = 0; p < 2; ++p)
        gload16(pqg + (p << 13) + (tid << 4), pq_s[0] + (p << 13) + (w << 10));

    const char* qgb = (const char*)Qb + ((size_t)bh * 4096 + n0 + (w << 6)) * 128;
    bf16x8 qa[4][2];
    float diag_l[4];
#pragma unroll
    for (int ni = 0; ni < 4; ++ni) {
        const char* qr = qgb + ((ni << 4) + lq) * 128;
        float ss = 0.f;
#pragma unroll
        for (int kk = 0; kk < 2; ++kk) {
            qa[ni][kk] = *(const bf16x8*)(qr + (kk << 6) + (lg << 4));
#pragma unroll
            for (int u = 0; u < 8; ++u) { float f = (float)qa[ni][kk][u]; ss += f * f; }
        }
        ss += __shfl_xor(ss, 16);
        ss += __shfl_xor(ss, 32);
        diag_l[ni] = DIAG_C * ss;
    }

    f32x4 acc2[4][5] = {};
    float mmax[4] = {-1e30f, -1e30f, -1e30f, -1e30f};
    char* tw = T_s + w * 5120;
    const f32x4 Zc = {0.f, 0.f, 0.f, 0.f};

    __syncthreads();

    for (int ft = 0; ft < 4; ++ft) {
        const int buf = ft & 1;
        if (ft < 3) {
#pragma unroll
            for (int p = 0; p < 2; ++p)
                gload16(pqg + ((ft + 1) << 14) + (p << 13) + (tid << 4),
                        pq_s[buf ^ 1] + (p << 13) + (w << 10));
        }
        const char* pqb = pq_s[buf];
#pragma unroll
        for (int sl = 0; sl < 4; ++sl) {
            f32x4 acc1[2][4];
#pragma unroll
            for (int mi = 0; mi < 2; ++mi) {
                const int fr = (sl << 5) + (mi << 4) + lq;
                bf16x8 pf = *(const bf16x8*)(pqb + fr * 128 +
                              (((lg << 4)) ^ ((lq & 7) << 4)));
#pragma unroll
                for (int ni = 0; ni < 4; ++ni)
                    acc1[mi][ni] = __builtin_amdgcn_mfma_f32_16x16x32_bf16(pf, qa[ni][0], Zc, 0, 0, 0);
            }
#pragma unroll
            for (int mi = 0; mi < 2; ++mi) {
                const int fr = (sl << 5) + (mi << 4) + lq;
                bf16x8 pf = *(const bf16x8*)(pqb + fr * 128 +
                              ((64 + (lg << 4)) ^ ((lq & 7) << 4)));
#pragma unroll
                for (int ni = 0; ni < 4; ++ni)
                    acc1[mi][ni] = __builtin_amdgcn_mfma_f32_16x16x32_bf16(pf, qa[ni][1], acc1[mi][ni], 0, 0, 0);
            }
#pragma unroll
            for (int mi = 0; mi < 2; ++mi)
#pragma unroll
                for (int ni = 0; ni < 4; ++ni) {
                    bf16x4 tv;
#pragma unroll
                    for (int r = 0; r < 4; ++r) {
                        const float qd = acc1[mi][ni][r];
                        mmax[ni] = fmaxf(mmax[ni], qd);
                        tv[r] = (bf16)__expf(NORMALIZER * qd - diag_l[ni]);
                    }
                    *(bf16x4*)(tw + ((ni << 4) + lq) * 80 + (mi << 5) + (lg << 3)) = tv;
                }
            bf16x8 ta[4];
#pragma unroll
            for (int ni = 0; ni < 4; ++ni)
                ta[ni] = *(const bf16x8*)(tw + ((ni << 4) + lq) * 80 + (lg << 4));
#pragma unroll
            for (int nj = 0; nj < 5; ++nj) {
                const int e = (nj << 4) + lq;
                bf16x8 cb = *(const bf16x8*)(ctx_s + e * 1024 +
                              (((ft << 8) + (sl << 6) + (lg << 4)) ^ ((e & 7) << 4)));
#pragma unroll
                for (int ni = 0; ni < 4; ++ni)
                    acc2[ni][nj] = __builtin_amdgcn_mfma_f32_16x16x32_bf16(ta[ni], cb, acc2[ni][nj], 0, 0, 0);
            }
        }
        __syncthreads();
    }

    const float sG = __expf(-gmax[0]);
    const float ess = esumsum[bh];
    bf16* outb = OutC + ((size_t)(b * 4096) + n0 + (w << 6)) * 512 + (h << 6);
#pragma unroll
    for (int ni = 0; ni < 4; ++ni) {
        float mmr = mmax[ni];
        mmr = fmaxf(mmr, __shfl_xor(mmr, 16));
        mmr = fmaxf(mmr, __shfl_xor(mmr, 32));
#pragma unroll
        for (int r = 0; r < 4; ++r) {
            const float mm = __shfl(mmr, (lg << 2) + r);
            const float uT = __shfl(acc2[ni][4][r], (lg << 4));
            const float uE = __shfl(acc2[ni][4][r], (lg << 4) | 1);
            const float cr = __expf(-NORMALIZER * mm);
            const float qsum = cr * uT + KEPS * 512.0f;
            const float D = sG * (cr * uE + KEPS * ess) + KEPS * 4096.0f * qsum;
            const float inv = 1.0f / D;
            const float al = sG * cr * inv;
            const float G1 = sG * KEPS * inv;
            const float G2 = KEPS * qsum * inv;
            const int row = (ni << 4) + (lg << 2) + r;
#pragma unroll
            for (int nj = 0; nj < 4; ++nj) {
                const int e = (nj << 4) + lq;
                float v = al * acc2[ni][nj][r] + G1 * ctxsum[(bh << 6) + e] + G2 * vsum[(bh << 6) + e];
                outb[(size_t)row * 512 + e] = (bf16)v;
            }
        }
    }
}

// ---------------------------------------------------------------------------
// LayerNorm over D=512 from bf16 hid, 4 rows per 256-thread block. Grid 4096.
// ---------------------------------------------------------------------------
__global__ __launch_bounds__(256)
void ln_kernel(const bf16* __restrict__ hid, const float* __restrict__ gamma,
               const float* __restrict__ beta, float* __restrict__ out)
{
    const int row = (blockIdx.x << 2) + (threadIdx.x >> 6);
    const int lane = threadIdx.x & 63;
    const bf16x8 hv = *(const bf16x8*)((const char*)hid + (size_t)row * 1024 + (lane << 4));
    float v[8];
    float s = 0.f, sq = 0.f;
#pragma unroll
    for (int u = 0; u < 8; ++u) {
        v[u] = (float)hv[u];
        s += v[u];
        sq += v[u] * v[u];
    }
    s = warpReduceSum(s);
    sq = warpReduceSum(sq);
    const float mu = s * 0.001953125f;
    const float var = sq * 0.001953125f - mu * mu;
    const float rs = rsqrtf(var + 1e-12f);
    const float4 g1 = *(const float4*)(gamma + (lane << 3));
    const float4 g2 = *(const float4*)(gamma + (lane << 3) + 4);
    const float4 b1 = *(const float4*)(beta + (lane << 3));
    const float4 b2 = *(const float4*)(beta + (lane << 3) + 4);
    float4 o1, o2;
    o1.x = (v[0] - mu) * rs * g1.x + b1.x;
    o1.y = (v[1] - mu) * rs * g1.y + b1.y;
    o1.z = (v[2] - mu) * rs * g1.z + b1.z;
    o1.w = (v[3] - mu) * rs * g1.w + b1.w;
    o2.x = (v[4] - mu) * rs * g2.x + b2.x;
    o2.y = (v[5] - mu) * rs * g2.y + b2.y;
    o2.z = (v[6] - mu) * rs * g2.z + b2.z;
    o2.w = (v[7] - mu) * rs * g2.w + b2.w;
    *(float4*)(out + (size_t)row * DMODEL + (lane << 3)) = o1;
    *(float4*)(out + (size_t)row * DMODEL + (lane << 3) + 4) = o2;
}

// ---------------------------------------------------------------------------
extern "C" void kernel_launch(void* const* d_in, const int* in_sizes, int n_in,
                              void* d_out, int out_size, void* d_ws, size_t ws_size,
                              hipStream_t stream)
{
    const float* x     = (const float*)d_in[0];
    const float* Wq    = (const float*)d_in[2];
    const float* bq    = (const float*)d_in[3];
    const float* Wk    = (const float*)d_in[4];
    const float* bk    = (const float*)d_in[5];
    const float* Wv    = (const float*)d_in[6];
    const float* bv    = (const float*)d_in[7];
    const float* projq = (const float*)d_in[8];
    const float* projk = (const float*)d_in[9];
    const float* Wd    = (const float*)d_in[10];
    const float* bd    = (const float*)d_in[11];
    const float* gamma = (const float*)d_in[12];
    const float* beta  = (const float*)d_in[13];

    char* W = (char*)d_ws;
    bf16*  qb16   = (bf16*) (W);                   // 16 MB [bh][n][64]; later hid bf16
    bf16*  kb16s  = (bf16*) (W + 16777216);        // 16 MB (swizzled rows)
    bf16*  vtb    = (bf16*) (W + 33554432);        // 16 MB (transposed+swizzled)
    bf16*  xb16   = (bf16*) (W + 50331648);        // 16 MB (x bf16, later ctx bf16)
    float* ctxp4  = (float*)(W + 67108864);        // 16 MB  [4][32][512][64] f32
    float* esumf4 = (float*)(W + 83886080);        // 256 KB [4][32][512] f32
    float* dgk    = (float*)(W + 84148224);        // 512 KB [32][4096] f32
    bf16*  Wb16   = (bf16*) (W + 100663296);       // 1.5 MB
    bf16*  Wdb16  = (bf16*) (W + 102236160);       // 0.5 MB
    bf16*  pqb16  = (bf16*) (W + 102760448);       // 64 KB (pre-swizzled)
    float* bcat   = (float*)(W + 102825984);       // 6 KB
    bf16*  ctxE   = (bf16*) (W + 102832128);       // 2.5 MB [32][80][512] swz
    float* vsumb  = (float*)(W + 105453568);       // 8 KB
    float* ctxsum = (float*)(W + 105461760);       // 8 KB
    float* esmsm  = (float*)(W + 105469952);       // 128 B
    float* gmaxb  = (float*)(W + 105470080);       // 4 B

    prep_convert<<<9250, 256, 0, stream>>>(x, Wq, Wk, Wv, Wd, projq, bq, bk, bv,
                                           xb16, Wb16, Wdb16, pqb16, bcat,
                                           ctxsum, esmsm, gmaxb);

    gemm_mfma<0><<<dim3(12, 128), 256, 0, stream>>>(xb16, Wb16, bcat, nullptr,
                                                    qb16, kb16s, vtb);

    vsum_diag_kernel<<<2048, 64, 0, stream>>>(vtb, kb16s, vsumb, dgk);
    kside_mfma2<<<dim3(32, 8, 4), 256, 0, stream>>>(kb16s, vtb, projk, dgk,
                                                    ctxp4, esumf4, gmaxb);
    finalize_ctx<<<dim3(32, 4), 256, 0, stream>>>(ctxp4, esumf4, ctxE, ctxsum, esmsm);

    qside_mfma4<<<dim3(32, 8), 512, 0, stream>>>(qb16, pqb16, ctxE, vsumb,
                                                 ctxsum, esmsm, gmaxb, xb16);

    // hid (bf16) -> qb16 region (dead after qside)
    gemm_mfma<1><<<dim3(4, 128), 256, 0, stream>>>(xb16, Wdb16, bd, x,
                                                   qb16, nullptr, nullptr);
    ln_kernel<<<4096, 256, 0, stream>>>(qb16, gamma, beta, (float*)d_out);
}

// Round 19
// 177.821 us; speedup vs baseline: 1.0927x; 1.0432x over previous
//
#include <hip/hip_runtime.h>
#include <math.h>

typedef __bf16 bf16;
typedef __bf16 bf16x8 __attribute__((ext_vector_type(8)));
typedef __bf16 bf16x4 __attribute__((ext_vector_type(4)));
typedef float  f32x4  __attribute__((ext_vector_type(4)));

#define NSEQ 4096
#define DMODEL 512
#define DHEAD 64
#define MFEAT 512
#define BHEADS 32
#define ROWS_TOTAL 16384

#define NORMALIZER 0.35355339059327373f
#define DIAG_C 0.0625f
#define KEPS 1e-4f

__device__ __forceinline__ float warpReduceSum(float v) {
#pragma unroll
    for (int off = 32; off > 0; off >>= 1) v += __shfl_xor(v, off);
    return v;
}

__device__ __forceinline__ void atomicMaxF(float* addr, float val) {
    int* ai = (int*)addr;
    int cur = __float_as_int(*addr);
    while (__int_as_float(cur) < val) {
        int prev = atomicCAS(ai, cur, __float_as_int(val));
        if (prev == cur) break;
        cur = prev;
    }
}

__device__ __forceinline__ void gload16(const void* g, void* l) {
    __builtin_amdgcn_global_load_lds((const __attribute__((address_space(1))) void*)g,
                                     (__attribute__((address_space(3))) void*)l, 16, 0, 0);
}

// ---------------------------------------------------------------------------
// prep: f32 -> bf16 conversions + weight concat + bias concat.
// pqb written PRE-SWIZZLED per 128B row: byte ^= (feat&7)<<4.
// Tail threads (e0 >= 9471488, 128 of them) zero ctxsum/vsum/esumsum + gmax.
// ---------------------------------------------------------------------------
__global__ __launch_bounds__(256)
void prep_convert(const float* __restrict__ x, const float* __restrict__ Wq,
                  const float* __restrict__ Wk, const float* __restrict__ Wv,
                  const float* __restrict__ Wd, const float* __restrict__ pq,
                  const float* __restrict__ bq, const float* __restrict__ bk,
                  const float* __restrict__ bv,
                  bf16* __restrict__ xb, bf16* __restrict__ Wb,
                  bf16* __restrict__ Wdb, bf16* __restrict__ pqb,
                  float* __restrict__ bcat, float* __restrict__ ctxsum,
                  float* __restrict__ vsumb,
                  float* __restrict__ esumsum, float* __restrict__ gmax)
{
    size_t i4 = (size_t)blockIdx.x * 256 + threadIdx.x;
    size_t e0 = i4 * 4;
    if (e0 >= 9471488) {
        const int t = (int)(i4 - 2367872);      // 0..127
        float4 z = {0.f, 0.f, 0.f, 0.f};
#pragma unroll
        for (int j = 0; j < 4; ++j) {
            *(float4*)(ctxsum + (t << 4) + (j << 2)) = z;
            *(float4*)(vsumb  + (t << 4) + (j << 2)) = z;
        }
        if (t < 32) esumsum[t] = 0.f;
        if (t == 0) *gmax = -1e30f;
        return;
    }
    const float* src;
    if (e0 < 8388608) {
        src = x + e0;
        float4 v = *(const float4*)src;
        bf16* d = xb + e0;
        d[0] = (bf16)v.x; d[1] = (bf16)v.y; d[2] = (bf16)v.z; d[3] = (bf16)v.w;
    } else if (e0 < 9175040) {
        size_t c = e0 - 8388608; int wsel = (int)(c >> 18); size_t o = c & 262143;
        src = (wsel == 0 ? Wq : wsel == 1 ? Wk : Wv) + o;
        float4 v = *(const float4*)src;
        bf16* d = Wb + c;
        d[0] = (bf16)v.x; d[1] = (bf16)v.y; d[2] = (bf16)v.z; d[3] = (bf16)v.w;
    } else if (e0 < 9437184) {
        size_t c = e0 - 9175040;
        src = Wd + c;
        float4 v = *(const float4*)src;
        bf16* d = Wdb + c;
        d[0] = (bf16)v.x; d[1] = (bf16)v.y; d[2] = (bf16)v.z; d[3] = (bf16)v.w;
    } else if (e0 < 9469952) {
        size_t c = e0 - 9437184;           // multiple of 4
        src = pq + c;
        float4 v = *(const float4*)src;
        const int feat = (int)(c >> 6), col = (int)(c & 63);
        bf16x4 d4;
        d4[0] = (bf16)v.x; d4[1] = (bf16)v.y; d4[2] = (bf16)v.z; d4[3] = (bf16)v.w;
        const int inrow = (col << 1) ^ ((feat & 7) << 4);
        *(bf16x4*)((char*)pqb + (size_t)feat * 128 + inrow) = d4;
    } else {
        size_t c = e0 - 9469952; int wsel = (int)(c >> 9); size_t o = c & 511;
        src = (wsel == 0 ? bq : wsel == 1 ? bk : bv) + o;
        *(float4*)(bcat + c) = *(const float4*)src;
    }
}

// ---------------------------------------------------------------------------
// bf16 MFMA GEMM, C = A * B^T (+bias)(+resid), 128x128 tile, BK=64.
// MODE 0: A=xb16, B=Wcat[1536x512]; Q->bf16 [bh][n][64]; K->bf16 swizzled rows
//         (+dgk inline); V->bf16 transposed [bh][e][n] swizzled (+vsum atomics).
// MODE 1: A=ctxb16, B=Wd; hid(bf16, via outQ ptr) = +bias +resid
// ---------------------------------------------------------------------------
template<int MODE>
__global__ __launch_bounds__(256)
void gemm_mfma(const bf16* __restrict__ A, const bf16* __restrict__ Bw,
               const float* __restrict__ bias, const float* __restrict__ resid,
               bf16* __restrict__ outQ, bf16* __restrict__ outK,
               bf16* __restrict__ outV, float* __restrict__ dgk,
               float* __restrict__ vsum)
{
    __shared__ char smem[32768];
    char* As = smem;
    char* Bs = smem + 16384;
    const int tid = threadIdx.x;
    const int w = tid >> 6, l = tid & 63;
    const int wr = w >> 1, wc = w & 1;
    const int row0 = blockIdx.y << 7;
    const int col0 = blockIdx.x << 7;

    f32x4 acc[4][4] = {};
    const char* Ab = (const char*)A + (size_t)row0 * 1024;
    const char* Bb = (const char*)Bw + (size_t)col0 * 1024;

    for (int kt = 0; kt < 8; ++kt) {
        const int k0b = kt << 7;
#pragma unroll
        for (int i = 0; i < 4; ++i) {
            int off = (i << 12) + (tid << 4);
            int g = off ^ ((off >> 3) & 0x70);
            int grow = g >> 7, gcol = g & 127;
            gload16(Ab + (size_t)grow * 1024 + k0b + gcol, As + (i << 12) + (w << 10));
            gload16(Bb + (size_t)grow * 1024 + k0b + gcol, Bs + (i << 12) + (w << 10));
        }
        __syncthreads();
#pragma unroll
        for (int ks = 0; ks < 2; ++ks) {
            bf16x8 af[4], bb[4];
#pragma unroll
            for (int mi = 0; mi < 4; ++mi) {
                int row = (wr << 6) + (mi << 4) + (l & 15);
                int addr = ((row << 7) + (ks << 6) + ((l >> 4) << 4)) ^ ((row & 7) << 4);
                af[mi] = *(const bf16x8*)(As + addr);
            }
#pragma unroll
            for (int nj = 0; nj < 4; ++nj) {
                int row = (wc << 6) + (nj << 4) + (l & 15);
                int addr = ((row << 7) + (ks << 6) + ((l >> 4) << 4)) ^ ((row & 7) << 4);
                bb[nj] = *(const bf16x8*)(Bs + addr);
            }
#pragma unroll
            for (int mi = 0; mi < 4; ++mi)
#pragma unroll
                for (int nj = 0; nj < 4; ++nj)
                    acc[mi][nj] = __builtin_amdgcn_mfma_f32_16x16x32_bf16(af[mi], bb[nj], acc[mi][nj], 0, 0, 0);
        }
        __syncthreads();
    }

    const int subrow = (l >> 4) << 2;
    const int subcol = l & 15;

    if (MODE == 0 && col0 < 1024) {
        // ---- LDS-transpose epilogue for Q and K stripes ----
#pragma unroll
        for (int mi = 0; mi < 4; ++mi)
#pragma unroll
            for (int nj = 0; nj < 4; ++nj) {
                const int coll = (wc << 6) + (nj << 4) + subcol;
                const float bi = bias[col0 + coll];
#pragma unroll
                for (int r = 0; r < 4; ++r) {
                    const int rowl = (wr << 6) + (mi << 4) + subrow + r;
                    *(bf16*)(smem + (rowl << 8) + (((coll << 1)) ^ ((rowl & 7) << 4))) =
                        (bf16)(acc[mi][nj][r] + bi);
                }
            }
        __syncthreads();
        const int trow = tid >> 1, thalf = tid & 1;
        const int rg = row0 + trow;
        const int bb2 = rg >> 12, n = rg & 4095;
        const char* src = smem + (trow << 8);
        const int sxor = (trow & 7) << 4;
        if (col0 < 512) {
            const int hh = (col0 >> 6) + thalf;
            char* dst = (char*)outQ + (((size_t)(bb2 * 8 + hh) * 4096 + n) << 7);
#pragma unroll
            for (int j = 0; j < 8; ++j)
                *(bf16x8*)(dst + (j << 4)) =
                    *(const bf16x8*)(src + (((thalf << 7) + (j << 4)) ^ sxor));
        } else {
            const int hh = ((col0 - 512) >> 6) + thalf;
            char* dst = (char*)outK + (size_t)rg * 1024 + hh * 128;
            float ss = 0.f;
#pragma unroll
            for (int j = 0; j < 8; ++j) {
                bf16x8 v = *(const bf16x8*)(src + (((thalf << 7) + (j << 4)) ^ sxor));
                *(bf16x8*)(dst + ((j << 4) ^ sxor)) = v;
#pragma unroll
                for (int u = 0; u < 8; ++u) { float f = (float)v[u]; ss += f * f; }
            }
            dgk[(size_t)(bb2 * 8 + hh) * 4096 + n] = DIAG_C * ss;
        }
        return;
    }

#pragma unroll
    for (int mi = 0; mi < 4; ++mi) {
#pragma unroll
        for (int nj = 0; nj < 4; ++nj) {
            const int cg = col0 + (wc << 6) + (nj << 4) + subcol;
            const float bi = bias[cg];
            const int rgb = row0 + (wr << 6) + (mi << 4) + subrow;
            if (MODE == 0) {
                // V stripe only (cg >= 1024)
                const int eg = cg - 1024, hh = eg >> 6, ee = eg & 63;
                const int bb2 = rgb >> 12, n = rgb & 4095;
                bf16x4 pv;
#pragma unroll
                for (int r = 0; r < 4; ++r) pv[r] = (bf16)(acc[mi][nj][r] + bi);
                const int nb = n * 2;
                size_t byteaddr = (size_t)((bb2 * 8 + hh) * 64 + ee) * 8192
                                + (size_t)((nb & ~127) | ((nb & 127) ^ ((ee & 7) << 4)));
                *(bf16x4*)((char*)outV + byteaddr) = pv;
            } else {
                // hid (bf16) via outQ pointer
#pragma unroll
                for (int r = 0; r < 4; ++r) {
                    const int rg = rgb + r;
                    outQ[(size_t)rg * 512 + cg] =
                        (bf16)(acc[mi][nj][r] + bi + resid[(size_t)rg * 512 + cg]);
                }
            }
        }
    }

    if (MODE == 0) {
        // ---- vsum partials from f32 acc (V stripe): 64 rows/wave per col ----
        const int bb2 = row0 >> 12;
#pragma unroll
        for (int nj = 0; nj < 4; ++nj) {
            const int cg = col0 + (wc << 6) + (nj << 4) + subcol;
            const float bi = bias[cg];
            float ps = 0.f;
#pragma unroll
            for (int mi = 0; mi < 4; ++mi)
#pragma unroll
                for (int r = 0; r < 4; ++r) ps += acc[mi][nj][r];
            ps += __shfl_xor(ps, 16);
            ps += __shfl_xor(ps, 32);
            if (l < 16) {
                const int eg = cg - 1024, hh = eg >> 6, ee = eg & 63;
                atomicAdd(&vsum[(bb2 * 8 + hh) * 64 + ee], ps + 64.f * bi);
            }
        }
    }
}

// ---------------------------------------------------------------------------
// kside MFMA: grid (32 bh, 8 m-tiles(64), 4 n-slices), block 256.
// ---------------------------------------------------------------------------
__global__ __launch_bounds__(256)
void kside_mfma2(const bf16* __restrict__ Kb, const bf16* __restrict__ Vt,
                 const float* __restrict__ projk, const float* __restrict__ dgk,
                 float* __restrict__ ctxp4, float* __restrict__ esumf4,
                 float* __restrict__ gmax)
{
    __shared__ char K_s[16384];
    __shared__ char V_s[16384];
    __shared__ char E_s[16384];
    __shared__ float part_s[4][64];
    __shared__ float wmax_s[4];

    const int tid = threadIdx.x;
    const int w = tid >> 6, l = tid & 63;
    const int bh = blockIdx.x;
    const int b = bh >> 3, h = bh & 7;
    const int m0 = blockIdx.y << 6;
    const int z = blockIdx.z;

    bf16x8 pk[4][2];
#pragma unroll
    for (int nj = 0; nj < 4; ++nj)
#pragma unroll
        for (int ks = 0; ks < 2; ++ks) {
            const int m = m0 + (nj << 4) + (l & 15);
            const int e0 = (ks << 5) + ((l >> 4) << 3);
            const float* p = projk + (size_t)m * 64 + e0;
            float4 a = *(const float4*)p;
            float4 c = *(const float4*)(p + 4);
            bf16x8 f;
            f[0] = (bf16)(NORMALIZER * a.x); f[1] = (bf16)(NORMALIZER * a.y);
            f[2] = (bf16)(NORMALIZER * a.z); f[3] = (bf16)(NORMALIZER * a.w);
            f[4] = (bf16)(NORMALIZER * c.x); f[5] = (bf16)(NORMALIZER * c.y);
            f[6] = (bf16)(NORMALIZER * c.z); f[7] = (bf16)(NORMALIZER * c.w);
            pk[nj][ks] = f;
        }

    const char* kg = (const char*)Kb + ((size_t)(b * 4096) * 512 + h * 64) * 2
                   + (size_t)((w << 3) + (l >> 3)) * 1024 + ((l & 7) << 4);
    const char* vg = (const char*)Vt + (size_t)bh * 64 * 8192
                   + (size_t)((w << 2) + (l >> 4)) * 8192 + ((l & 15) << 4);
    const float* dgb = dgk + (bh << 12) + (z << 10);

    float esacc[4] = {0.f, 0.f, 0.f, 0.f};
    float lmax = -1e30f;
    f32x4 acc2[4] = {};

    for (int c = 0; c < 8; ++c) {
        const int n0 = (z << 10) + (c << 7);
#pragma unroll
        for (int i = 0; i < 4; ++i) {
            gload16(kg + (size_t)(n0 + (i << 5)) * 1024, K_s + (i << 12) + (w << 10));
            gload16(vg + (size_t)(i << 4) * 8192 + (n0 << 1), V_s + (i << 12) + (w << 10));
        }
        __syncthreads();

        f32x4 acc1[2][4] = {};
        __builtin_amdgcn_s_setprio(1);
#pragma unroll
        for (int ks = 0; ks < 2; ++ks) {
            bf16x8 af[2];
#pragma unroll
            for (int mi = 0; mi < 2; ++mi) {
                const int n = (w << 5) + (mi << 4) + (l & 15);
                const int addr = ((n << 7) + (ks << 6) + ((l >> 4) << 4)) ^ ((n & 7) << 4);
                af[mi] = *(const bf16x8*)(K_s + addr);
            }
#pragma unroll
            for (int mi = 0; mi < 2; ++mi)
#pragma unroll
                for (int nj = 0; nj < 4; ++nj)
                    acc1[mi][nj] = __builtin_amdgcn_mfma_f32_16x16x32_bf16(af[mi], pk[nj][ks], acc1[mi][nj], 0, 0, 0);
        }
        __builtin_amdgcn_s_setprio(0);
        float dgr[2][4];
#pragma unroll
        for (int mi = 0; mi < 2; ++mi) {
            float4 dv = *(const float4*)(dgb + (c << 7) + (w << 5) + (mi << 4) + ((l >> 4) << 2));
            dgr[mi][0] = dv.x; dgr[mi][1] = dv.y; dgr[mi][2] = dv.z; dgr[mi][3] = dv.w;
        }
#pragma unroll
        for (int mi = 0; mi < 2; ++mi) {
            const int nrow0 = (w << 5) + (mi << 4) + ((l >> 4) << 2);
#pragma unroll
            for (int nj = 0; nj < 4; ++nj) {
                const int m = (nj << 4) + (l & 15);
                bf16x4 ev;
#pragma unroll
                for (int r = 0; r < 4; ++r) {
                    const float d = acc1[mi][nj][r];
                    lmax = fmaxf(lmax, d);
                    const float e = __expf(d - dgr[mi][r]);
                    esacc[nj] += e;
                    ev[r] = (bf16)e;
                }
                const int addr = ((m << 8) + (nrow0 << 1)) ^ ((m & 7) << 4);
                *(bf16x4*)(E_s + addr) = ev;
            }
        }
        __syncthreads();

        __builtin_amdgcn_s_setprio(1);
#pragma unroll
        for (int ks = 0; ks < 4; ++ks) {
            const int mrow = (w << 4) + (l & 15);
            const int aaddr = ((mrow << 8) + (ks << 6) + ((l >> 4) << 4)) ^ ((mrow & 7) << 4);
            bf16x8 aE = *(const bf16x8*)(E_s + aaddr);
#pragma unroll
            for (int ej = 0; ej < 4; ++ej) {
                const int e = (ej << 4) + (l & 15);
                const int vaddr = ((e << 8) + (ks << 6) + ((l >> 4) << 4)) ^ ((e & 7) << 4);
                bf16x8 bV = *(const bf16x8*)(V_s + vaddr);
                acc2[ej] = __builtin_amdgcn_mfma_f32_16x16x32_bf16(aE, bV, acc2[ej], 0, 0, 0);
            }
        }
        __builtin_amdgcn_s_setprio(0);
        __syncthreads();
    }

#pragma unroll
    for (int nj = 0; nj < 4; ++nj) {
        float s = esacc[nj];
        s += __shfl_xor(s, 16); s += __shfl_xor(s, 32);
        if (l < 16) part_s[w][(nj << 4) + l] = s;
    }
#pragma unroll
    for (int off = 32; off > 0; off >>= 1) lmax = fmaxf(lmax, __shfl_xor(lmax, off));
    if (l == 0) wmax_s[w] = lmax;
    __syncthreads();
    if (tid < 64) {
        float es = part_s[0][tid] + part_s[1][tid] + part_s[2][tid] + part_s[3][tid];
        esumf4[((size_t)z * 32 + bh) * 512 + m0 + tid] = es;
        if (tid == 0)
            atomicMaxF(gmax, fmaxf(fmaxf(wmax_s[0], wmax_s[1]), fmaxf(wmax_s[2], wmax_s[3])));
    }
    const size_t zbase = (size_t)z * (32 * 512 * 64);
    const int mrow0 = m0 + (w << 4) + ((l >> 4) << 2);
#pragma unroll
    for (int ej = 0; ej < 4; ++ej) {
        const int e = (ej << 4) + (l & 15);
#pragma unroll
        for (int r = 0; r < 4; ++r)
            ctxp4[zbase + ((size_t)(bh * 512 + mrow0 + r)) * 64 + e] = acc2[ej][r];
    }
}

// ---------------------------------------------------------------------------
// finalize: sum 4 partials -> ctxE bf16 [bh][80][1024B rows, PRE-SWIZZLED
// byte ^= (e&7)<<4]; rows 64=ones, 65=esum; ctxsum (atomic); esumsum.
// Grid (32 bh, 4 m-chunks), block 256.
// ---------------------------------------------------------------------------
__global__ __launch_bounds__(256)
void finalize_ctx(const float* __restrict__ ctxp4, const float* __restrict__ esumf4,
                  bf16* __restrict__ ctxE, float* __restrict__ ctxsum,
                  float* __restrict__ esumsum)
{
    __shared__ float red_s[4][64];
    const int tid = threadIdx.x;
    const int bh = blockIdx.x;
    const int m0 = blockIdx.y << 7;
    const int e = tid & 63, ms = tid >> 6;
    const size_t Z = (size_t)32 * 512 * 64;

    const float* cb = ctxp4 + ((size_t)bh * 512 + m0 + ms * 32) * 64 + e;
    char* obr = (char*)ctxE + ((size_t)bh * 80 + e) * 1024;
    float s = 0.f;
#pragma unroll
    for (int i8 = 0; i8 < 4; ++i8) {
        bf16x8 pk8;
#pragma unroll
        for (int u = 0; u < 8; ++u) {
            const size_t off = (size_t)(i8 * 8 + u) * 64;
            float v = cb[off] + cb[off + Z] + cb[off + 2 * Z] + cb[off + 3 * Z];
            s += v;
            pk8[u] = (bf16)v;
        }
        const int inrow = ((m0 + ms * 32 + i8 * 8) << 1) ^ ((e & 7) << 4);
        *(bf16x8*)(obr + inrow) = pk8;
    }
    red_s[ms][e] = s;
    __syncthreads();
    if (tid < 64)
        atomicAdd(ctxsum + bh * 64 + tid,
                  red_s[0][tid] + red_s[1][tid] + red_s[2][tid] + red_s[3][tid]);
    if (tid < 128) {
        const int m = m0 + tid;
        float ev = esumf4[(size_t)bh * 512 + m]
                 + esumf4[((size_t)32 + bh) * 512 + m]
                 + esumf4[((size_t)64 + bh) * 512 + m]
                 + esumf4[((size_t)96 + bh) * 512 + m];
        bf16* er = ctxE + (size_t)(bh * 80 + 64) * 512;
        er[m] = (bf16)1.0f;                 // row 64 (e&7==0: no swizzle)
        er[512 + (m ^ 8)] = (bf16)ev;       // row 65: byte (m*2)^16 => elem m^8
        float t = warpReduceSum(ev);
        if ((tid & 63) == 0) atomicAdd(esumsum + bh, t);
    }
}

// ---------------------------------------------------------------------------
// q-side v4: 512 threads (8 waves), 512 q-rows/block, grid (32 bh, 8).
// ---------------------------------------------------------------------------
__global__ __launch_bounds__(512, 1)
void qside_mfma4(const bf16* __restrict__ Qb, const bf16* __restrict__ Pq,
                 const bf16* __restrict__ CtxE, const float* __restrict__ vsum,
                 const float* __restrict__ ctxsum, const float* __restrict__ esumsum,
                 const float* __restrict__ gmax, bf16* __restrict__ OutC)
{
    __shared__ char ctx_s[81920];        // [80 e][1024B] swizzled
    __shared__ char pq_s[2][16384];      // [128 feat][128B] swizzled
    __shared__ char T_s[40960];          // 8 waves x 64 rows x 80B

    const int tid = threadIdx.x;
    const int w = tid >> 6, l = tid & 63;
    const int lq = l & 15, lg = l >> 4;
    const int bh = blockIdx.x;
    const int b = bh >> 3, h = bh & 7;
    const int n0 = blockIdx.y << 9;

    const char* ctxg = (const char*)CtxE + (size_t)bh * 81920;
    const char* pqg  = (const char*)Pq;
#pragma unroll
    for (int i = 0; i < 10; ++i)
        gload16(ctxg + (i << 13) + (tid << 4), ctx_s + (i << 13) + (w << 10));
#pragma unroll
    for (int p = 0; p < 2; ++p)
        gload16(pqg + (p << 13) + (tid << 4), pq_s[0] + (p << 13) + (w << 10));

    const char* qgb = (const char*)Qb + ((size_t)bh * 4096 + n0 + (w << 6)) * 128;
    bf16x8 qa[4][2];
    float diag_l[4];
#pragma unroll
    for (int ni = 0; ni < 4; ++ni) {
        const char* qr = qgb + ((ni << 4) + lq) * 128;
        float ss = 0.f;
#pragma unroll
        for (int kk = 0; kk < 2; ++kk) {
            qa[ni][kk] = *(const bf16x8*)(qr + (kk << 6) + (lg << 4));
#pragma unroll
            for (int u = 0; u < 8; ++u) { float f = (float)qa[ni][kk][u]; ss += f * f; }
        }
        ss += __shfl_xor(ss, 16);
        ss += __shfl_xor(ss, 32);
        diag_l[ni] = DIAG_C * ss;
    }

    f32x4 acc2[4][5] = {};
    float mmax[4] = {-1e30f, -1e30f, -1e30f, -1e30f};
    char* tw = T_s + w * 5120;
    const f32x4 Zc = {0.f, 0.f, 0.f, 0.f};

    __syncthreads();

    for (int ft = 0; ft < 4; ++ft) {
        const int buf = ft & 1;
        if (ft < 3) {
#pragma unroll
            for (int p = 0; p < 2; ++p)
                gload16(pqg + ((ft + 1) << 14) + (p << 13) + (tid << 4),
                        pq_s[buf ^ 1] + (p << 13) + (w << 10));
        }
        const char* pqb = pq_s[buf];
#pragma unroll
        for (int sl = 0; sl < 4; ++sl) {
            f32x4 acc1[2][4];
#pragma unroll
            for (int mi = 0; mi < 2; ++mi) {
                const int fr = (sl << 5) + (mi << 4) + lq;
                bf16x8 pf = *(const bf16x8*)(pqb + fr * 128 +
                              (((lg << 4)) ^ ((lq & 7) << 4)));
#pragma unroll
                for (int ni = 0; ni < 4; ++ni)
                    acc1[mi][ni] = __builtin_amdgcn_mfma_f32_16x16x32_bf16(pf, qa[ni][0], Zc, 0, 0, 0);
            }
#pragma unroll
            for (int mi = 0; mi < 2; ++mi) {
                const int fr = (sl << 5) + (mi << 4) + lq;
                bf16x8 pf = *(const bf16x8*)(pqb + fr * 128 +
                              ((64 + (lg << 4)) ^ ((lq & 7) << 4)));
#pragma unroll
                for (int ni = 0; ni < 4; ++ni)
                    acc1[mi][ni] = __builtin_amdgcn_mfma_f32_16x16x32_bf16(pf, qa[ni][1], acc1[mi][ni], 0, 0, 0);
            }
#pragma unroll
            for (int mi = 0; mi < 2; ++mi)
#pragma unroll
                for (int ni = 0; ni < 4; ++ni) {
                    bf16x4 tv;
#pragma unroll
                    for (int r = 0; r < 4; ++r) {
                        const float qd = acc1[mi][ni][r];
                        mmax[ni] = fmaxf(mmax[ni], qd);
                        tv[r] = (bf16)__expf(NORMALIZER * qd - diag_l[ni]);
                    }
                    *(bf16x4*)(tw + ((ni << 4) + lq) * 80 + (mi << 5) + (lg << 3)) = tv;
                }
            bf16x8 ta[4];
#pragma unroll
            for (int ni = 0; ni < 4; ++ni)
                ta[ni] = *(const bf16x8*)(tw + ((ni << 4) + lq) * 80 + (lg << 4));
#pragma unroll
            for (int nj = 0; nj < 5; ++nj) {
                const int e = (nj << 4) + lq;
                bf16x8 cb = *(const bf16x8*)(ctx_s + e * 1024 +
                              (((ft << 8) + (sl << 6) + (lg << 4)) ^ ((e & 7) << 4)));
#pragma unroll
                for (int ni = 0; ni < 4; ++ni)
                    acc2[ni][nj] = __builtin_amdgcn_mfma_f32_16x16x32_bf16(ta[ni], cb, acc2[ni][nj], 0, 0, 0);
            }
        }
        __syncthreads();
    }

    const float sG = __expf(-gmax[0]);
    const float ess = esumsum[bh];
    bf16* outb = OutC + ((size_t)(b * 4096) + n0 + (w << 6)) * 512 + (h << 6);
#pragma unroll
    for (int ni = 0; ni < 4; ++ni) {
        float mmr = mmax[ni];
        mmr = fmaxf(mmr, __shfl_xor(mmr, 16));
        mmr = fmaxf(mmr, __shfl_xor(mmr, 32));
#pragma unroll
        for (int r = 0; r < 4; ++r) {
            const float mm = __shfl(mmr, (lg << 2) + r);
            const float uT = __shfl(acc2[ni][4][r], (lg << 4));
            const float uE = __shfl(acc2[ni][4][r], (lg << 4) | 1);
            const float cr = __expf(-NORMALIZER * mm);
            const float qsum = cr * uT + KEPS * 512.0f;
            const float D = sG * (cr * uE + KEPS * ess) + KEPS * 4096.0f * qsum;
            const float inv = 1.0f / D;
            const float al = sG * cr * inv;
            const float G1 = sG * KEPS * inv;
            const float G2 = KEPS * qsum * inv;
            const int row = (ni << 4) + (lg << 2) + r;
#pragma unroll
            for (int nj = 0; nj < 4; ++nj) {
                const int e = (nj << 4) + lq;
                float v = al * acc2[ni][nj][r] + G1 * ctxsum[(bh << 6) + e] + G2 * vsum[(bh << 6) + e];
                outb[(size_t)row * 512 + e] = (bf16)v;
            }
        }
    }
}

// ---------------------------------------------------------------------------
// LayerNorm over D=512 from bf16 hid, 4 rows per 256-thread block. Grid 4096.
// ---------------------------------------------------------------------------
__global__ __launch_bounds__(256)
void ln_kernel(const bf16* __restrict__ hid, const float* __restrict__ gamma,
               const float* __restrict__ beta, float* __restrict__ out)
{
    const int row = (blockIdx.x << 2) + (threadIdx.x >> 6);
    const int lane = threadIdx.x & 63;
    const bf16x8 hv = *(const bf16x8*)((const char*)hid + (size_t)row * 1024 + (lane << 4));
    float v[8];
    float s = 0.f, sq = 0.f;
#pragma unroll
    for (int u = 0; u < 8; ++u) {
        v[u] = (float)hv[u];
        s += v[u];
        sq += v[u] * v[u];
    }
    s = warpReduceSum(s);
    sq = warpReduceSum(sq);
    const float mu = s * 0.001953125f;
    const float var = sq * 0.001953125f - mu * mu;
    const float rs = rsqrtf(var + 1e-12f);
    const float4 g1 = *(const float4*)(gamma + (lane << 3));
    const float4 g2 = *(const float4*)(gamma + (lane << 3) + 4);
    const float4 b1 = *(const float4*)(beta + (lane << 3));
    const float4 b2 = *(const float4*)(beta + (lane << 3) + 4);
    float4 o1, o2;
    o1.x = (v[0] - mu) * rs * g1.x + b1.x;
    o1.y = (v[1] - mu) * rs * g1.y + b1.y;
    o1.z = (v[2] - mu) * rs * g1.z + b1.z;
    o1.w = (v[3] - mu) * rs * g1.w + b1.w;
    o2.x = (v[4] - mu) * rs * g2.x + b2.x;
    o2.y = (v[5] - mu) * rs * g2.y + b2.y;
    o2.z = (v[6] - mu) * rs * g2.z + b2.z;
    o2.w = (v[7] - mu) * rs * g2.w + b2.w;
    *(float4*)(out + (size_t)row * DMODEL + (lane << 3)) = o1;
    *(float4*)(out + (size_t)row * DMODEL + (lane << 3) + 4) = o2;
}

// ---------------------------------------------------------------------------
extern "C" void kernel_launch(void* const* d_in, const int* in_sizes, int n_in,
                              void* d_out, int out_size, void* d_ws, size_t ws_size,
                              hipStream_t stream)
{
    const float* x     = (const float*)d_in[0];
    const float* Wq    = (const float*)d_in[2];
    const float* bq    = (const float*)d_in[3];
    const float* Wk    = (const float*)d_in[4];
    const float* bk    = (const float*)d_in[5];
    const float* Wv    = (const float*)d_in[6];
    const float* bv    = (const float*)d_in[7];
    const float* projq = (const float*)d_in[8];
    const float* projk = (const float*)d_in[9];
    const float* Wd    = (const float*)d_in[10];
    const float* bd    = (const float*)d_in[11];
    const float* gamma = (const float*)d_in[12];
    const float* beta  = (const float*)d_in[13];

    char* W = (char*)d_ws;
    bf16*  qb16   = (bf16*) (W);                   // 16 MB [bh][n][64]; later hid bf16
    bf16*  kb16s  = (bf16*) (W + 16777216);        // 16 MB (swizzled rows)
    bf16*  vtb    = (bf16*) (W + 33554432);        // 16 MB (transposed+swizzled)
    bf16*  xb16   = (bf16*) (W + 50331648);        // 16 MB (x bf16, later ctx bf16)
    float* ctxp4  = (float*)(W + 67108864);        // 16 MB  [4][32][512][64] f32
    float* esumf4 = (float*)(W + 83886080);        // 256 KB [4][32][512] f32
    float* dgk    = (float*)(W + 84148224);        // 512 KB [32][4096] f32
    bf16*  Wb16   = (bf16*) (W + 100663296);       // 1.5 MB
    bf16*  Wdb16  = (bf16*) (W + 102236160);       // 0.5 MB
    bf16*  pqb16  = (bf16*) (W + 102760448);       // 64 KB (pre-swizzled)
    float* bcat   = (float*)(W + 102825984);       // 6 KB
    bf16*  ctxE   = (bf16*) (W + 102832128);       // 2.5 MB [32][80][512] swz
    float* vsumb  = (float*)(W + 105453568);       // 8 KB
    float* ctxsum = (float*)(W + 105461760);       // 8 KB
    float* esmsm  = (float*)(W + 105469952);       // 128 B
    float* gmaxb  = (float*)(W + 105470080);       // 4 B

    prep_convert<<<9250, 256, 0, stream>>>(x, Wq, Wk, Wv, Wd, projq, bq, bk, bv,
                                           xb16, Wb16, Wdb16, pqb16, bcat,
                                           ctxsum, vsumb, esmsm, gmaxb);

    gemm_mfma<0><<<dim3(12, 128), 256, 0, stream>>>(xb16, Wb16, bcat, nullptr,
                                                    qb16, kb16s, vtb, dgk, vsumb);

    kside_mfma2<<<dim3(32, 8, 4), 256, 0, stream>>>(kb16s, vtb, projk, dgk,
                                                    ctxp4, esumf4, gmaxb);
    finalize_ctx<<<dim3(32, 4), 256, 0, stream>>>(ctxp4, esumf4, ctxE, ctxsum, esmsm);

    qside_mfma4<<<dim3(32, 8), 512, 0, stream>>>(qb16, pqb16, ctxE, vsumb,
                                                 ctxsum, esmsm, gmaxb, xb16);

    // hid (bf16) -> qb16 region (dead after qside)
    gemm_mfma<1><<<dim3(4, 128), 256, 0, stream>>>(xb16, Wdb16, bd, x,
                                                   qb16, nullptr, nullptr,
                                                   nullptr, nullptr);
    ln_kernel<<<4096, 256, 0, stream>>>(qb16, gamma, beta, (float*)d_out);
}